// Round 6
// baseline (2176.224 us; speedup 1.0000x reference)
//
#include <hip/hip_runtime.h>
#include <hip/hip_bf16.h>

#define DEVFN __device__ __forceinline__

#if defined(__has_builtin)
#if __has_builtin(__builtin_amdgcn_global_load_lds)
#define HAS_GLL 1
#else
#define HAS_GLL 0
#endif
#else
#define HAS_GLL 0
#endif

// async global->LDS, 16B per lane; LDS dest must be linear in lane order
DEVFN void gload_lds16(const float* g, float* l) {
#if HAS_GLL
    __builtin_amdgcn_global_load_lds(
        (const __attribute__((address_space(1))) void*)g,
        (__attribute__((address_space(3))) void*)l, 16, 0, 0);
#else
    *(float4*)l = *(const float4*)g;
#endif
}

// ---------------- debug signal ----------------
__global__ void k_signal(float* out, float v) {
    if (threadIdx.x == 0 && blockIdx.x == 0) out[0] = v;
}

// ---------------- int-width detect + normalize ----------------
__global__ void k_detect64(const long long* __restrict__ p, int count, int* flag) {
    if (threadIdx.x == 0 && blockIdx.x == 0) {
        int ok = 1;
        for (int i = 0; i < count; i++) {
            long long v = p[i];
            if (v < 0 || v >= (1LL << 30)) { ok = 0; break; }
        }
        *flag = ok;
    }
}

__global__ __launch_bounds__(256) void k_cvt_idx(const void* __restrict__ p, int n,
                                                 const int* __restrict__ flag,
                                                 int* __restrict__ out) {
    int i = blockIdx.x * 256 + threadIdx.x;
    if (i >= n) return;
    if (*flag) out[i] = (int)((const long long*)p)[i];
    else       out[i] = ((const int*)p)[i];
}

// ---------------- FC1: h1T = relu(x @ w1 + b1)^T, stored [512][128] (k-major for FC2) ----
__global__ __launch_bounds__(256) void k_fc1(const float* __restrict__ x,
                                             const float* __restrict__ w,
                                             const float* __restrict__ b,
                                             float* __restrict__ out) {
    int j = blockIdx.x * 256 + threadIdx.x;   // 512
    int m = blockIdx.y;                       // 128
    float acc = b[j];
    const float* xr = x + m * 128;
    for (int k = 0; k < 128; k++)
        acc = fmaf(xr[k], w[k * 512 + j], acc);
    out[j * 128 + m] = fmaxf(acc, 0.f);       // transposed store
}

// ---------------- FC2 GEMM v6: C[128,110592] = h1[128,512] @ w2 + b ----------------
// m97-pattern staging: global_load_lds width=16 (no VGPR round-trip, no staging
// addr-VALU) + KT=16 double-buffered 2-phase (stage next || compute cur, one
// __syncthreads per tile drains the prefetch after compute hides HBM latency).
// Tile 128x128, 256 thr, micro 8x8. LDS 2*(8+8)=32KB. A k-major from h1t ->
// both stages are linear-in-lane-order (global_load_lds dest constraint).
__global__ __launch_bounds__(256) void k_fc2_gemm6(const float* __restrict__ h1t,
                                                   const float* __restrict__ w,
                                                   const float* __restrict__ bias,
                                                   float* __restrict__ out) {
    const int N = 110592;
    constexpr int KT = 16, NT = 128;
    __shared__ float At[2 * KT * 128];   // [buf][k][row]
    __shared__ float Bt[2 * KT * NT];    // [buf][k][col]

    const int tid = threadIdx.x;
    const int cg = tid & 15;             // 16 col-groups
    const int rg = tid >> 4;             // 16 row-groups of 8 rows
    const int nbase = blockIdx.x * NT;
    const int r0 = rg * 8;
    const int c0 = cg * 4;               // cols {c0..c0+3} U {c0+64..c0+67}

    float acc[8][8];
#pragma unroll
    for (int j = 0; j < 4; j++) {
        float bj0 = bias[nbase + c0 + j];
        float bj1 = bias[nbase + 64 + c0 + j];
#pragma unroll
        for (int r = 0; r < 8; r++) { acc[r][j] = bj0; acc[r][j + 4] = bj1; }
    }

    // stage tile at k0 into buffer `buf`: A = contiguous 8KB, B = 16 rows x 512B
    auto stage = [&](int buf, int k0) {
#pragma unroll
        for (int it = 0; it < 2; it++) {
            int idx = tid + it * 256;                       // float4 index, 0..511
            gload_lds16(h1t + (size_t)k0 * 128 + idx * 4,
                        At + buf * (KT * 128) + idx * 4);
        }
#pragma unroll
        for (int it = 0; it < 2; it++) {
            int idx = tid + it * 256;
            int kk = idx >> 5, c4 = (idx & 31) * 4;
            gload_lds16(w + (size_t)(k0 + kk) * N + nbase + c4,
                        Bt + buf * (KT * NT) + idx * 4);    // linear: idx*4 = kk*128+c4
        }
    };

    auto compute = [&](int buf) {
        const float* Ab = At + buf * (KT * 128);
        const float* Bb = Bt + buf * (KT * NT);
#pragma unroll
        for (int k = 0; k < KT; k++) {
            float4 a0 = *(const float4*)(Ab + k * 128 + r0);
            float4 a1 = *(const float4*)(Ab + k * 128 + r0 + 4);
            float4 b0 = *(const float4*)(Bb + k * NT + c0);
            float4 b1 = *(const float4*)(Bb + k * NT + c0 + 64);
            float av[8] = {a0.x, a0.y, a0.z, a0.w, a1.x, a1.y, a1.z, a1.w};
            float bv[8] = {b0.x, b0.y, b0.z, b0.w, b1.x, b1.y, b1.z, b1.w};
#pragma unroll
            for (int r = 0; r < 8; r++)
#pragma unroll
                for (int j = 0; j < 8; j++)
                    acc[r][j] = fmaf(av[r], bv[j], acc[r][j]);
        }
    };

    // 32 K-tiles, 2-phase pipeline with compile-time buffer indices
    stage(0, 0);
    __syncthreads();
#pragma unroll 1
    for (int t = 0; t + 2 < 32; t += 2) {
        stage(1, (t + 1) * KT);
        compute(0);
        __syncthreads();
        stage(0, (t + 2) * KT);
        compute(1);
        __syncthreads();
    }
    stage(1, 31 * KT);
    compute(0);
    __syncthreads();
    compute(1);

#pragma unroll
    for (int r = 0; r < 8; r++) {
        int m = r0 + r;
        float4 o0 = {acc[r][0], acc[r][1], acc[r][2], acc[r][3]};
        float4 o1 = {acc[r][4], acc[r][5], acc[r][6], acc[r][7]};
        *(float4*)(out + (size_t)m * N + nbase + c0) = o0;
        *(float4*)(out + (size_t)m * N + nbase + c0 + 64) = o1;
    }
}

// ---------------- graph build ----------------
__global__ __launch_bounds__(256) void k_zero_int(int* p, int n) {
    int i = blockIdx.x * 256 + threadIdx.x;
    if (i < n) p[i] = 0;
}

__global__ __launch_bounds__(256) void k_deg(const int* __restrict__ dst, int e,
                                             int* __restrict__ deg) {
    int i = blockIdx.x * 256 + threadIdx.x;
    if (i < e) atomicAdd(&deg[dst[i]], 1);
}

__global__ __launch_bounds__(256) void k_dinv(const int* __restrict__ deg,
                                              float* __restrict__ dinv, int n) {
    int i = blockIdx.x * 256 + threadIdx.x;
    if (i < n) dinv[i] = deg[i] > 0 ? 1.0f / sqrtf((float)deg[i]) : 0.0f;
}

// exclusive scan of deg[0..n) -> row_ptr[0..n], single block of 256 threads
__global__ __launch_bounds__(256) void k_scan(const int* __restrict__ deg,
                                              int* __restrict__ row_ptr, int n) {
    __shared__ int part[256];
    int tid = threadIdx.x;
    int per = (n + 255) / 256;
    int start = tid * per;
    int end = min(start + per, n);
    int s = 0;
    for (int i = start; i < end; i++) s += deg[i];
    part[tid] = s;
    __syncthreads();
    for (int off = 1; off < 256; off <<= 1) {
        int t = (tid >= off) ? part[tid - off] : 0;
        __syncthreads();
        part[tid] += t;
        __syncthreads();
    }
    int base = (tid == 0) ? 0 : part[tid - 1];
    int run = base;
    for (int i = start; i < end; i++) { row_ptr[i] = run; run += deg[i]; }
    if (tid == 255) row_ptr[n] = part[255];
}

__global__ __launch_bounds__(256) void k_fill(const int* __restrict__ src,
                                              const int* __restrict__ dst, int e,
                                              const int* __restrict__ row_ptr,
                                              int* __restrict__ cnt,
                                              const float* __restrict__ dinv,
                                              int* __restrict__ col, float* __restrict__ val) {
    int i = blockIdx.x * 256 + threadIdx.x;
    if (i >= e) return;
    int d = dst[i], s = src[i];
    int slot = row_ptr[d] + atomicAdd(&cnt[d], 1);
    col[slot] = s;
    val[slot] = -dinv[s] * dinv[d];
}

// ---------------- prop v2 (float4 channels) ----------------
template <int CI, int MODE>
__global__ __launch_bounds__(256) void k_prop2(const float* __restrict__ h,
                                               const float* __restrict__ sub,
                                               const int* __restrict__ row_ptr,
                                               const int* __restrict__ col,
                                               const float* __restrict__ val,
                                               float* __restrict__ out, int n) {
    constexpr int C4 = CI / 4;
    constexpr int BY = 256 / C4;
    int c4 = threadIdx.x;
    int d = blockIdx.x;
    int b = blockIdx.y * BY + threadIdx.y;
    int p0 = row_ptr[d], p1 = row_ptr[d + 1];
    float4 acc = {0.f, 0.f, 0.f, 0.f};
    const float4* hb = (const float4*)h + (size_t)b * n * C4;
    for (int p = p0; p < p1; p++) {
        float vp = val[p];
        float4 hv = hb[(size_t)col[p] * C4 + c4];
        acc.x = fmaf(vp, hv.x, acc.x);
        acc.y = fmaf(vp, hv.y, acc.y);
        acc.z = fmaf(vp, hv.z, acc.z);
        acc.w = fmaf(vp, hv.w, acc.w);
    }
    size_t oi = ((size_t)b * n + d) * C4 + c4;
    if (MODE) {
        float4 s = ((const float4*)sub)[oi];
        acc.x = 2.f * acc.x - s.x;
        acc.y = 2.f * acc.y - s.y;
        acc.z = 2.f * acc.z - s.z;
        acc.w = 2.f * acc.w - s.w;
    }
    ((float4*)out)[oi] = acc;
}

// ---------------- cheb einsum GEMM v3 (LDS-tiled) ----------------
// C[M,CO] = sum_t Tt[M,CI]@Wt + bias, lrelu, optional repeat.
// Block: MT rows x CO cols, MT = 1024/(CO/8). Thread: 4 rows x 8 cols.
template <int CI, int CO, bool REPEAT>
__global__ __launch_bounds__(256) void k_cheb_gemm3(const float* __restrict__ t0,
                                                    const float* __restrict__ t1,
                                                    const float* __restrict__ t2,
                                                    const float* __restrict__ W,
                                                    const float* __restrict__ bias,
                                                    float* __restrict__ out, int n) {
    constexpr int CGN = CO / 8;         // col-groups
    constexpr int MT = 1024 / CGN;      // rows per block (CO=128:64, 64:128, 32:256)
    constexpr int KT = 32, AST = 37;
    __shared__ float At[MT * AST];
    __shared__ float Wt_s[KT * CO];

    const int tid = threadIdx.x;
    const int cg = tid % CGN;
    const int rg = tid / CGN;
    const int m_base = blockIdx.x * MT;
    const int c0 = cg * 8;

    float acc[4][8];
#pragma unroll
    for (int jj = 0; jj < 8; jj++) {
        float bj = bias[c0 + jj];
#pragma unroll
        for (int r = 0; r < 4; r++) acc[r][jj] = bj;
    }

    const float* As[3] = {t0, t1, t2};
#pragma unroll 1
    for (int t = 0; t < 3; t++) {
        const float* A = As[t];
        const float* Wg = W + t * CI * CO;
#pragma unroll 1
        for (int k0 = 0; k0 < CI; k0 += KT) {
            __syncthreads();
            // A chunk: MT rows x 32 k  (MT*8 float4)
#pragma unroll
            for (int it = 0; it < MT / 32; it++) {
                int idx = tid + it * 256;
                int row = idx >> 3, k4 = (idx & 7) * 4;
                float4 a = *(const float4*)(A + (size_t)(m_base + row) * CI + k0 + k4);
                float* dst = At + row * AST + k4;
                dst[0] = a.x; dst[1] = a.y; dst[2] = a.z; dst[3] = a.w;
            }
            // W chunk: 32 k x CO
#pragma unroll
            for (int it = 0; it < (KT * CO) / 1024; it++) {
                int idx = tid + it * 256;
                int kk = idx / (CO / 4), c4 = (idx % (CO / 4)) * 4;
                *(float4*)(Wt_s + kk * CO + c4) =
                    *(const float4*)(Wg + (k0 + kk) * CO + c4);
            }
            __syncthreads();
#pragma unroll 4
            for (int k = 0; k < KT; k++) {
                float a0 = At[(rg * 4 + 0) * AST + k];
                float a1 = At[(rg * 4 + 1) * AST + k];
                float a2 = At[(rg * 4 + 2) * AST + k];
                float a3 = At[(rg * 4 + 3) * AST + k];
                float4 w0 = *(const float4*)(Wt_s + k * CO + c0);
                float4 w1 = *(const float4*)(Wt_s + k * CO + c0 + 4);
                float wv[8] = {w0.x, w0.y, w0.z, w0.w, w1.x, w1.y, w1.z, w1.w};
#pragma unroll
                for (int jj = 0; jj < 8; jj++) {
                    acc[0][jj] = fmaf(a0, wv[jj], acc[0][jj]);
                    acc[1][jj] = fmaf(a1, wv[jj], acc[1][jj]);
                    acc[2][jj] = fmaf(a2, wv[jj], acc[2][jj]);
                    acc[3][jj] = fmaf(a3, wv[jj], acc[3][jj]);
                }
            }
        }
    }

#pragma unroll
    for (int r = 0; r < 4; r++) {
        int m = m_base + rg * 4 + r;
#pragma unroll
        for (int jj = 0; jj < 8; jj++) {
            float v = acc[r][jj];
            acc[r][jj] = v >= 0.f ? v : 0.2f * v;   // lrelu
        }
        float4 o0 = {acc[r][0], acc[r][1], acc[r][2], acc[r][3]};
        float4 o1 = {acc[r][4], acc[r][5], acc[r][6], acc[r][7]};
        if (REPEAT) {
            int b = m / n, d = m - (m / n) * n;
            size_t ob = ((size_t)b * (2 * n) + 2 * d) * CO + c0;
            *(float4*)(out + ob) = o0;
            *(float4*)(out + ob + 4) = o1;
            *(float4*)(out + ob + CO) = o0;
            *(float4*)(out + ob + CO + 4) = o1;
        } else {
            *(float4*)(out + (size_t)m * CO + c0) = o0;
            *(float4*)(out + (size_t)m * CO + c0 + 4) = o1;
        }
    }
}

// ---------------- cheb small GEMM (CI=32, CO=16): LDS-staged, coalesced ----------------
__global__ __launch_bounds__(256) void k_cheb_small(const float* __restrict__ t0,
                                                    const float* __restrict__ t1,
                                                    const float* __restrict__ t2,
                                                    const float* __restrict__ W,
                                                    const float* __restrict__ bias,
                                                    float* __restrict__ out) {
    constexpr int CI = 32, CO = 16, MT = 256, AST = 33;
    __shared__ float At[MT * AST];      // 33.8 KB
    __shared__ float Ws[3 * CI * CO];   // 6 KB

    const int tid = threadIdx.x;
    const int cg = tid & 1;             // 2 col-groups of 8
    const int rg = tid >> 1;            // 128 row-groups; rows rg and rg+128
    const int c0 = cg * 8;
    const int m_base = blockIdx.x * MT;

    // stage all weights once: 3*32*16 = 1536 floats = 384 float4 (256 threads -> strided)
    for (int i = tid; i < 384; i += 256)
        ((float4*)Ws)[i] = ((const float4*)W)[i];

    float acc[2][8];
#pragma unroll
    for (int jj = 0; jj < 8; jj++) {
        float bj = bias[c0 + jj];
        acc[0][jj] = bj; acc[1][jj] = bj;
    }

    const float* As[3] = {t0, t1, t2};
#pragma unroll 1
    for (int t = 0; t < 3; t++) {
        const float* A = As[t];
        __syncthreads();
        // stage A tile: 256 rows x 32 k = 2048 float4, 8 per thread, coalesced
#pragma unroll
        for (int it = 0; it < 8; it++) {
            int idx = tid + it * 256;
            int row = idx >> 3, k4 = (idx & 7) * 4;
            float4 a = *(const float4*)(A + (size_t)(m_base + row) * CI + k4);
            float* dst = At + row * AST + k4;
            dst[0] = a.x; dst[1] = a.y; dst[2] = a.z; dst[3] = a.w;
        }
        __syncthreads();
        const float* Wt = Ws + t * CI * CO;
#pragma unroll 8
        for (int k = 0; k < CI; k++) {
            float a0 = At[rg * AST + k];
            float a1 = At[(rg + 128) * AST + k];
            float4 w0 = *(const float4*)(Wt + k * CO + c0);
            float4 w1 = *(const float4*)(Wt + k * CO + c0 + 4);
            float wv[8] = {w0.x, w0.y, w0.z, w0.w, w1.x, w1.y, w1.z, w1.w};
#pragma unroll
            for (int jj = 0; jj < 8; jj++) {
                acc[0][jj] = fmaf(a0, wv[jj], acc[0][jj]);
                acc[1][jj] = fmaf(a1, wv[jj], acc[1][jj]);
            }
        }
    }

#pragma unroll
    for (int r = 0; r < 2; r++) {
        int m = m_base + rg + r * 128;
#pragma unroll
        for (int jj = 0; jj < 8; jj++) {
            float v = acc[r][jj];
            acc[r][jj] = v >= 0.f ? v : 0.2f * v;   // lrelu
        }
        float4 o0 = {acc[r][0], acc[r][1], acc[r][2], acc[r][3]};
        float4 o1 = {acc[r][4], acc[r][5], acc[r][6], acc[r][7]};
        *(float4*)(out + (size_t)m * CO + c0) = o0;
        *(float4*)(out + (size_t)m * CO + c0 + 4) = o1;
    }
}

// ---------------- final conv: ci=16, co=3 ----------------
__global__ __launch_bounds__(256) void k_final_conv(const float* __restrict__ t0,
                                                    const float* __restrict__ t1,
                                                    const float* __restrict__ t2,
                                                    const float* __restrict__ W,
                                                    const float* __restrict__ bias,
                                                    float* __restrict__ out, int M) {
    int m = blockIdx.x * 256 + threadIdx.x;
    if (m >= M) return;
    float a0 = bias[0], a1 = bias[1], a2 = bias[2];
    const float* hs[3] = {t0, t1, t2};
#pragma unroll
    for (int t = 0; t < 3; t++) {
        const float4* h4 = (const float4*)(hs[t] + (size_t)m * 16);
        const float* Wt = W + t * 48;
#pragma unroll
        for (int q = 0; q < 4; q++) {
            float4 hv = h4[q];
            const float* Wq = Wt + q * 12;
            a0 = fmaf(hv.x, Wq[0], a0); a1 = fmaf(hv.x, Wq[1], a1); a2 = fmaf(hv.x, Wq[2], a2);
            a0 = fmaf(hv.y, Wq[3], a0); a1 = fmaf(hv.y, Wq[4], a1); a2 = fmaf(hv.y, Wq[5], a2);
            a0 = fmaf(hv.z, Wq[6], a0); a1 = fmaf(hv.z, Wq[7], a1); a2 = fmaf(hv.z, Wq[8], a2);
            a0 = fmaf(hv.w, Wq[9], a0); a1 = fmaf(hv.w, Wq[10], a1); a2 = fmaf(hv.w, Wq[11], a2);
        }
    }
    out[(size_t)m * 3 + 0] = a0;
    out[(size_t)m * 3 + 1] = a1;
    out[(size_t)m * 3 + 2] = a2;
}

// ---------------- permute + slice (f32 output) ----------------
__global__ __launch_bounds__(256) void k_permute(const float* __restrict__ h,
                                                 const int* __restrict__ perm,
                                                 float* __restrict__ out) {
    const int V = 6890, N = 6912;
    int idx = blockIdx.x * 256 + threadIdx.x;
    if (idx >= 128 * V * 3) return;
    int c = idx % 3;
    int t = idx / 3;
    int v = t % V;
    int b = t / V;
    int p = perm[v];
    out[idx] = h[((size_t)b * N + p) * 3 + c];
}

extern "C" void kernel_launch(void* const* d_in, const int* in_sizes, int n_in,
                              void* d_out, int out_size, void* d_ws, size_t ws_size,
                              hipStream_t stream) {
    float* out = (float*)d_out;

    static const int SIZES[20] = {
        16384, 65536, 512, 56623104, 110592,
        49152, 128, 24576, 64, 6144, 32, 1536, 16, 144, 3,
        10368, 20736, 41472, 82944, 6912
    };
    const void* in[20];
    bool map_ok = (n_in == 20);
    if (map_ok) {
        for (int s = 0; s < 20; s++) {
            int found = -1;
            for (int i = 0; i < n_in; i++)
                if (in_sizes[i] == SIZES[s]) { found = i; break; }
            if (found < 0) { map_ok = false; break; }
            in[s] = d_in[found];
        }
    }
    if (!map_ok)
        for (int i = 0; i < 20 && i < n_in; i++) in[i] = d_in[i];

    const float* x     = (const float*)in[0];
    const float* fc_w1 = (const float*)in[1];
    const float* fc_b1 = (const float*)in[2];
    const float* fc_w2 = (const float*)in[3];
    const float* fc_b2 = (const float*)in[4];
    const float* W0 = (const float*)in[5];
    const float* b0 = (const float*)in[6];
    const float* W1 = (const float*)in[7];
    const float* b1 = (const float*)in[8];
    const float* W2 = (const float*)in[9];
    const float* b2 = (const float*)in[10];
    const float* W3 = (const float*)in[11];
    const float* b3 = (const float*)in[12];
    const float* W4 = (const float*)in[13];
    const float* b4 = (const float*)in[14];

    const size_t SZ = 28311552;  // 128*1728*128 max buffer elems
    float* ws = (float*)d_ws;
    float* buf0 = ws;
    float* buf1 = ws + SZ;
    float* buf2 = ws + 2 * SZ;
    float* buf3 = ws + 3 * SZ;
    float* h1   = ws + 4 * SZ;           // 65536 (stored transposed [512][128])
    float* dinv = h1 + 65536;            // 6912
    float* val  = dinv + 6912;           // 41472
    int* ideg = (int*)(val + 41472);     // 6912
    int* rowp = ideg + 6912;             // 6913
    int* cnt  = rowp + 6913;             // 6912
    int* col  = cnt + 6912;              // 41472
    int* e0 = col + 41472;               // 10368
    int* e1 = e0 + 10368;                // 20736
    int* e2 = e1 + 20736;                // 41472
    int* e3 = e2 + 41472;                // 82944
    int* pm = e3 + 82944;                // 6912
    int* flag = pm + 6912;               // 1
    size_t needed = (char*)(flag + 1) - (char*)d_ws;
    if (ws_size < needed) {
        k_signal<<<1, 64, 0, stream>>>(out, 1000.0f);
        return;
    }

    // --- normalize integer inputs ---
    k_detect64<<<1, 64, 0, stream>>>((const long long*)in[15], 64, flag);
    k_cvt_idx<<<(10368 + 255) / 256, 256, 0, stream>>>(in[15], 10368, flag, e0);
    k_cvt_idx<<<(20736 + 255) / 256, 256, 0, stream>>>(in[16], 20736, flag, e1);
    k_cvt_idx<<<(41472 + 255) / 256, 256, 0, stream>>>(in[17], 41472, flag, e2);
    k_cvt_idx<<<(82944 + 255) / 256, 256, 0, stream>>>(in[18], 82944, flag, e3);
    k_cvt_idx<<<(6912 + 255) / 256, 256, 0, stream>>>(in[19], 6912, flag, pm);

    // FC1 (transposed h1) + FC2 v6
    k_fc1<<<dim3(2, 128), 256, 0, stream>>>(x, fc_w1, fc_b1, h1);
    k_fc2_gemm6<<<864, 256, 0, stream>>>(h1, fc_w2, fc_b2, buf0);

    auto build = [&](const int* edge, int e, int n) {
        int nb_n = (n + 255) / 256, nb_e = (e + 255) / 256;
        k_zero_int<<<nb_n, 256, 0, stream>>>(ideg, n);
        k_zero_int<<<nb_n, 256, 0, stream>>>(cnt, n);
        k_deg<<<nb_e, 256, 0, stream>>>(edge + e, e, ideg);
        k_dinv<<<nb_n, 256, 0, stream>>>(ideg, dinv, n);
        k_scan<<<1, 256, 0, stream>>>(ideg, rowp, n);
        k_fill<<<nb_e, 256, 0, stream>>>(edge, edge + e, e, rowp, cnt, dinv, col, val);
    };

    // Layer 0: n=864, ci=128, co=128 -> repeat to 1728 (MT=64 -> 1728 blocks)
    build(e0, 6 * 864, 864);
    k_prop2<128, 0><<<dim3(864, 16), dim3(32, 8), 0, stream>>>(buf0, buf0, rowp, col, val, buf1, 864);
    k_prop2<128, 1><<<dim3(864, 16), dim3(32, 8), 0, stream>>>(buf1, buf0, rowp, col, val, buf2, 864);
    k_cheb_gemm3<128, 128, true><<<1728, 256, 0, stream>>>(buf0, buf1, buf2, W0, b0, buf3, 864);

    // Layer 1: n=1728, ci=128, co=64 -> repeat to 3456 (MT=128 -> 1728 blocks)
    build(e1, 6 * 1728, 1728);
    k_prop2<128, 0><<<dim3(1728, 16), dim3(32, 8), 0, stream>>>(buf3, buf3, rowp, col, val, buf1, 1728);
    k_prop2<128, 1><<<dim3(1728, 16), dim3(32, 8), 0, stream>>>(buf1, buf3, rowp, col, val, buf2, 1728);
    k_cheb_gemm3<128, 64, true><<<1728, 256, 0, stream>>>(buf3, buf1, buf2, W1, b1, buf0, 1728);

    // Layer 2: n=3456, ci=64, co=32 -> repeat to 6912 (MT=256 -> 1728 blocks)
    build(e2, 6 * 3456, 3456);
    k_prop2<64, 0><<<dim3(3456, 8), dim3(16, 16), 0, stream>>>(buf0, buf0, rowp, col, val, buf1, 3456);
    k_prop2<64, 1><<<dim3(3456, 8), dim3(16, 16), 0, stream>>>(buf1, buf0, rowp, col, val, buf2, 3456);
    k_cheb_gemm3<64, 32, true><<<1728, 256, 0, stream>>>(buf0, buf1, buf2, W2, b2, buf3, 3456);

    // Layer 3: n=6912, ci=32, co=16, lrelu, NO repeat
    build(e3, 6 * 6912, 6912);
    k_prop2<32, 0><<<dim3(6912, 4), dim3(8, 32), 0, stream>>>(buf3, buf3, rowp, col, val, buf1, 6912);
    k_prop2<32, 1><<<dim3(6912, 4), dim3(8, 32), 0, stream>>>(buf1, buf3, rowp, col, val, buf2, 6912);
    k_cheb_small<<<3456, 256, 0, stream>>>(buf3, buf1, buf2, W3, b3, buf0);

    // Layer 4: n=6912, ci=16, co=3
    k_prop2<16, 0><<<dim3(6912, 2), dim3(4, 64), 0, stream>>>(buf0, buf0, rowp, col, val, buf1, 6912);
    k_prop2<16, 1><<<dim3(6912, 2), dim3(4, 64), 0, stream>>>(buf1, buf0, rowp, col, val, buf2, 6912);
    k_final_conv<<<(884736 + 255) / 256, 256, 0, stream>>>(buf0, buf1, buf2, W4, b4, buf3, 884736);

    // Permute + slice, f32 output
    int tot = 128 * 6890 * 3;
    k_permute<<<(tot + 255) / 256, 256, 0, stream>>>(buf3, pm, out);

    if (!map_ok) k_signal<<<1, 64, 0, stream>>>(out, 2000.0f);
}

// Round 7
// 1962.300 us; speedup vs baseline: 1.1090x; 1.1090x over previous
//
#include <hip/hip_runtime.h>
#include <hip/hip_bf16.h>

#define DEVFN __device__ __forceinline__

// ---------------- debug signal ----------------
__global__ void k_signal(float* out, float v) {
    if (threadIdx.x == 0 && blockIdx.x == 0) out[0] = v;
}

// ---------------- int-width detect + normalize ----------------
__global__ void k_detect64(const long long* __restrict__ p, int count, int* flag) {
    if (threadIdx.x == 0 && blockIdx.x == 0) {
        int ok = 1;
        for (int i = 0; i < count; i++) {
            long long v = p[i];
            if (v < 0 || v >= (1LL << 30)) { ok = 0; break; }
        }
        *flag = ok;
    }
}

__global__ __launch_bounds__(256) void k_cvt_idx(const void* __restrict__ p, int n,
                                                 const int* __restrict__ flag,
                                                 int* __restrict__ out) {
    int i = blockIdx.x * 256 + threadIdx.x;
    if (i >= n) return;
    if (*flag) out[i] = (int)((const long long*)p)[i];
    else       out[i] = ((const int*)p)[i];
}

// ---------------- FC1: h1 = relu(x @ w1 + b1), (128,128)@(128,512), row-major ----------
__global__ __launch_bounds__(256) void k_fc1(const float* __restrict__ x,
                                             const float* __restrict__ w,
                                             const float* __restrict__ b,
                                             float* __restrict__ out) {
    int j = blockIdx.x * 256 + threadIdx.x;   // 512
    int m = blockIdx.y;                       // 128
    float acc = b[j];
    const float* xr = x + m * 128;
    for (int k = 0; k < 128; k++)
        acc = fmaf(xr[k], w[k * 512 + j], acc);
    out[m * 512 + j] = fmaxf(acc, 0.f);
}

// ---------------- FC2 LDS-tiled GEMM v3 (proven 196us): C[128,110592] ----------------
__global__ __launch_bounds__(256) void k_fc2_gemm3(const float* __restrict__ h1,
                                                   const float* __restrict__ w,
                                                   const float* __restrict__ bias,
                                                   float* __restrict__ out) {
    const int N = 110592, K = 512;
    constexpr int KT = 32, MT = 128, NT = 64, AST = 37;
    __shared__ float At[MT * AST];
    __shared__ float Bt[KT * NT];

    const int tid = threadIdx.x;
    const int cg = tid & 7;
    const int rg = tid >> 3;
    const int nbase = blockIdx.x * NT;
    const int c0 = cg * 8;

    float acc[4][8];
#pragma unroll
    for (int jj = 0; jj < 8; jj++) {
        float bj = bias[nbase + c0 + jj];
#pragma unroll
        for (int r = 0; r < 4; r++) acc[r][jj] = bj;
    }

    for (int k0 = 0; k0 < K; k0 += KT) {
        __syncthreads();
#pragma unroll
        for (int it = 0; it < 4; it++) {
            int idx = tid + it * 256;
            int row = idx >> 3, k4 = (idx & 7) * 4;
            float4 a = *(const float4*)(h1 + row * K + k0 + k4);
            float* dst = At + row * AST + k4;
            dst[0] = a.x; dst[1] = a.y; dst[2] = a.z; dst[3] = a.w;
        }
#pragma unroll
        for (int it = 0; it < 2; it++) {
            int idx = tid + it * 256;
            int kk = idx >> 4, c4 = (idx & 15) * 4;
            *(float4*)(Bt + kk * NT + c4) =
                *(const float4*)(w + (size_t)(k0 + kk) * N + nbase + c4);
        }
        __syncthreads();
#pragma unroll 4
        for (int k = 0; k < KT; k++) {
            float a0 = At[(rg * 4 + 0) * AST + k];
            float a1 = At[(rg * 4 + 1) * AST + k];
            float a2 = At[(rg * 4 + 2) * AST + k];
            float a3 = At[(rg * 4 + 3) * AST + k];
            float4 w0 = *(const float4*)(Bt + k * NT + c0);
            float4 w1 = *(const float4*)(Bt + k * NT + c0 + 4);
            float wv[8] = {w0.x, w0.y, w0.z, w0.w, w1.x, w1.y, w1.z, w1.w};
#pragma unroll
            for (int jj = 0; jj < 8; jj++) {
                acc[0][jj] = fmaf(a0, wv[jj], acc[0][jj]);
                acc[1][jj] = fmaf(a1, wv[jj], acc[1][jj]);
                acc[2][jj] = fmaf(a2, wv[jj], acc[2][jj]);
                acc[3][jj] = fmaf(a3, wv[jj], acc[3][jj]);
            }
        }
    }
#pragma unroll
    for (int r = 0; r < 4; r++) {
        int m = rg * 4 + r;
        float4 o0 = {acc[r][0], acc[r][1], acc[r][2], acc[r][3]};
        float4 o1 = {acc[r][4], acc[r][5], acc[r][6], acc[r][7]};
        *(float4*)(out + (size_t)m * N + nbase + c0) = o0;
        *(float4*)(out + (size_t)m * N + nbase + c0 + 4) = o1;
    }
}

// ---------------- graph build ----------------
__global__ __launch_bounds__(256) void k_zero_int(int* p, int n) {
    int i = blockIdx.x * 256 + threadIdx.x;
    if (i < n) p[i] = 0;
}

__global__ __launch_bounds__(256) void k_deg(const int* __restrict__ dst, int e,
                                             int* __restrict__ deg) {
    int i = blockIdx.x * 256 + threadIdx.x;
    if (i < e) atomicAdd(&deg[dst[i]], 1);
}

__global__ __launch_bounds__(256) void k_dinv(const int* __restrict__ deg,
                                              float* __restrict__ dinv, int n) {
    int i = blockIdx.x * 256 + threadIdx.x;
    if (i < n) dinv[i] = deg[i] > 0 ? 1.0f / sqrtf((float)deg[i]) : 0.0f;
}

__global__ __launch_bounds__(256) void k_scan(const int* __restrict__ deg,
                                              int* __restrict__ row_ptr, int n) {
    __shared__ int part[256];
    int tid = threadIdx.x;
    int per = (n + 255) / 256;
    int start = tid * per;
    int end = min(start + per, n);
    int s = 0;
    for (int i = start; i < end; i++) s += deg[i];
    part[tid] = s;
    __syncthreads();
    for (int off = 1; off < 256; off <<= 1) {
        int t = (tid >= off) ? part[tid - off] : 0;
        __syncthreads();
        part[tid] += t;
        __syncthreads();
    }
    int base = (tid == 0) ? 0 : part[tid - 1];
    int run = base;
    for (int i = start; i < end; i++) { row_ptr[i] = run; run += deg[i]; }
    if (tid == 255) row_ptr[n] = part[255];
}

__global__ __launch_bounds__(256) void k_fill(const int* __restrict__ src,
                                              const int* __restrict__ dst, int e,
                                              const int* __restrict__ row_ptr,
                                              int* __restrict__ cnt,
                                              const float* __restrict__ dinv,
                                              int* __restrict__ col, float* __restrict__ val) {
    int i = blockIdx.x * 256 + threadIdx.x;
    if (i >= e) return;
    int d = dst[i], s = src[i];
    int slot = row_ptr[d] + atomicAdd(&cnt[d], 1);
    col[slot] = s;
    val[slot] = -dinv[s] * dinv[d];
}

// ---------------- prop v2 (float4 channels) ----------------
template <int CI, int MODE>
__global__ __launch_bounds__(256) void k_prop2(const float* __restrict__ h,
                                               const float* __restrict__ sub,
                                               const int* __restrict__ row_ptr,
                                               const int* __restrict__ col,
                                               const float* __restrict__ val,
                                               float* __restrict__ out, int n) {
    constexpr int C4 = CI / 4;
    constexpr int BY = 256 / C4;
    int c4 = threadIdx.x;
    int d = blockIdx.x;
    int b = blockIdx.y * BY + threadIdx.y;
    int p0 = row_ptr[d], p1 = row_ptr[d + 1];
    float4 acc = {0.f, 0.f, 0.f, 0.f};
    const float4* hb = (const float4*)h + (size_t)b * n * C4;
    for (int p = p0; p < p1; p++) {
        float vp = val[p];
        float4 hv = hb[(size_t)col[p] * C4 + c4];
        acc.x = fmaf(vp, hv.x, acc.x);
        acc.y = fmaf(vp, hv.y, acc.y);
        acc.z = fmaf(vp, hv.z, acc.z);
        acc.w = fmaf(vp, hv.w, acc.w);
    }
    size_t oi = ((size_t)b * n + d) * C4 + c4;
    if (MODE) {
        float4 s = ((const float4*)sub)[oi];
        acc.x = 2.f * acc.x - s.x;
        acc.y = 2.f * acc.y - s.y;
        acc.z = 2.f * acc.z - s.z;
        acc.w = 2.f * acc.w - s.w;
    }
    ((float4*)out)[oi] = acc;
}

// ---------------- cheb einsum GEMM v3 (layer 0 only) ----------------
template <int CI, int CO, bool REPEAT>
__global__ __launch_bounds__(256) void k_cheb_gemm3(const float* __restrict__ t0,
                                                    const float* __restrict__ t1,
                                                    const float* __restrict__ t2,
                                                    const float* __restrict__ W,
                                                    const float* __restrict__ bias,
                                                    float* __restrict__ out, int n) {
    constexpr int CGN = CO / 8;
    constexpr int MT = 1024 / CGN;
    constexpr int KT = 32, AST = 37;
    __shared__ float At[MT * AST];
    __shared__ float Wt_s[KT * CO];

    const int tid = threadIdx.x;
    const int cg = tid % CGN;
    const int rg = tid / CGN;
    const int m_base = blockIdx.x * MT;
    const int c0 = cg * 8;

    float acc[4][8];
#pragma unroll
    for (int jj = 0; jj < 8; jj++) {
        float bj = bias[c0 + jj];
#pragma unroll
        for (int r = 0; r < 4; r++) acc[r][jj] = bj;
    }

    const float* As[3] = {t0, t1, t2};
#pragma unroll 1
    for (int t = 0; t < 3; t++) {
        const float* A = As[t];
        const float* Wg = W + t * CI * CO;
#pragma unroll 1
        for (int k0 = 0; k0 < CI; k0 += KT) {
            __syncthreads();
#pragma unroll
            for (int it = 0; it < MT / 32; it++) {
                int idx = tid + it * 256;
                int row = idx >> 3, k4 = (idx & 7) * 4;
                float4 a = *(const float4*)(A + (size_t)(m_base + row) * CI + k0 + k4);
                float* dst = At + row * AST + k4;
                dst[0] = a.x; dst[1] = a.y; dst[2] = a.z; dst[3] = a.w;
            }
#pragma unroll
            for (int it = 0; it < (KT * CO) / 1024; it++) {
                int idx = tid + it * 256;
                int kk = idx / (CO / 4), c4 = (idx % (CO / 4)) * 4;
                *(float4*)(Wt_s + kk * CO + c4) =
                    *(const float4*)(Wg + (k0 + kk) * CO + c4);
            }
            __syncthreads();
#pragma unroll 4
            for (int k = 0; k < KT; k++) {
                float a0 = At[(rg * 4 + 0) * AST + k];
                float a1 = At[(rg * 4 + 1) * AST + k];
                float a2 = At[(rg * 4 + 2) * AST + k];
                float a3 = At[(rg * 4 + 3) * AST + k];
                float4 w0 = *(const float4*)(Wt_s + k * CO + c0);
                float4 w1 = *(const float4*)(Wt_s + k * CO + c0 + 4);
                float wv[8] = {w0.x, w0.y, w0.z, w0.w, w1.x, w1.y, w1.z, w1.w};
#pragma unroll
                for (int jj = 0; jj < 8; jj++) {
                    acc[0][jj] = fmaf(a0, wv[jj], acc[0][jj]);
                    acc[1][jj] = fmaf(a1, wv[jj], acc[1][jj]);
                    acc[2][jj] = fmaf(a2, wv[jj], acc[2][jj]);
                    acc[3][jj] = fmaf(a3, wv[jj], acc[3][jj]);
                }
            }
        }
    }

#pragma unroll
    for (int r = 0; r < 4; r++) {
        int m = m_base + rg * 4 + r;
#pragma unroll
        for (int jj = 0; jj < 8; jj++) {
            float v = acc[r][jj];
            acc[r][jj] = v >= 0.f ? v : 0.2f * v;   // lrelu
        }
        float4 o0 = {acc[r][0], acc[r][1], acc[r][2], acc[r][3]};
        float4 o1 = {acc[r][4], acc[r][5], acc[r][6], acc[r][7]};
        if (REPEAT) {
            int b = m / n, d = m - (m / n) * n;
            size_t ob = ((size_t)b * (2 * n) + 2 * d) * CO + c0;
            *(float4*)(out + ob) = o0;
            *(float4*)(out + ob + 4) = o1;
            *(float4*)(out + ob + CO) = o0;
            *(float4*)(out + ob + CO + 4) = o1;
        } else {
            *(float4*)(out + (size_t)m * CO + c0) = o0;
            *(float4*)(out + (size_t)m * CO + c0 + 4) = o1;
        }
    }
}

// ---------------- W-commute GEMM: A = T0(W0-W2)+b, B = T0 W1, C = T0 W2 ----------------
// out = A + P*B + 2*P*(P*C)  (P acts on nodes, W on channels -> they commute).
// Reads ONE T-matrix instead of three; no lrelu here (applied in prop_comb).
// outA: [m][CO]; outBC: [m][2*CO] with B at 0..CO-1, C at CO..2CO-1.
template <int CI, int CO>
__global__ __launch_bounds__(256) void k_cheb_gemmABC(const float* __restrict__ t0,
                                                      const float* __restrict__ W,
                                                      const float* __restrict__ bias,
                                                      float* __restrict__ outA,
                                                      float* __restrict__ outBC) {
    constexpr int CGN = CO / 8;         // 8 (CO=64) or 4 (CO=32)
    constexpr int MT = 1024 / CGN;      // 128 or 256
    constexpr int KT = 32, AST = 37;
    __shared__ float At[MT * AST];      // <= 37.9 KB
    __shared__ float Ws[3 * KT * CO];   // <= 24 KB

    const int tid = threadIdx.x;
    const int cg = tid % CGN;
    const int rg = tid / CGN;
    const int m_base = blockIdx.x * MT;
    const int c0 = cg * 8;

    float acc[3][4][8] = {};            // [t][row][col]

#pragma unroll 1
    for (int k0 = 0; k0 < CI; k0 += KT) {
        __syncthreads();
        // A chunk: MT rows x 32 k
#pragma unroll
        for (int it = 0; it < MT / 32; it++) {
            int idx = tid + it * 256;
            int row = idx >> 3, k4 = (idx & 7) * 4;
            float4 a = *(const float4*)(t0 + (size_t)(m_base + row) * CI + k0 + k4);
            float* dst = At + row * AST + k4;
            dst[0] = a.x; dst[1] = a.y; dst[2] = a.z; dst[3] = a.w;
        }
        // W chunks: 3 x (32 k x CO)
#pragma unroll
        for (int t = 0; t < 3; t++)
#pragma unroll
            for (int it = 0; it < CO / 32; it++) {
                int idx = tid + it * 256;
                int kk = idx / (CO / 4), c4 = (idx % (CO / 4)) * 4;
                *(float4*)(Ws + t * KT * CO + kk * CO + c4) =
                    *(const float4*)(W + t * CI * CO + (size_t)(k0 + kk) * CO + c4);
            }
        __syncthreads();
#pragma unroll 2
        for (int k = 0; k < KT; k++) {
            float a0 = At[(rg * 4 + 0) * AST + k];
            float a1 = At[(rg * 4 + 1) * AST + k];
            float a2 = At[(rg * 4 + 2) * AST + k];
            float a3 = At[(rg * 4 + 3) * AST + k];
#pragma unroll
            for (int t = 0; t < 3; t++) {
                float4 w0 = *(const float4*)(Ws + t * KT * CO + k * CO + c0);
                float4 w1 = *(const float4*)(Ws + t * KT * CO + k * CO + c0 + 4);
                float wv[8] = {w0.x, w0.y, w0.z, w0.w, w1.x, w1.y, w1.z, w1.w};
#pragma unroll
                for (int jj = 0; jj < 8; jj++) {
                    acc[t][0][jj] = fmaf(a0, wv[jj], acc[t][0][jj]);
                    acc[t][1][jj] = fmaf(a1, wv[jj], acc[t][1][jj]);
                    acc[t][2][jj] = fmaf(a2, wv[jj], acc[t][2][jj]);
                    acc[t][3][jj] = fmaf(a3, wv[jj], acc[t][3][jj]);
                }
            }
        }
    }

#pragma unroll
    for (int r = 0; r < 4; r++) {
        size_t m = m_base + rg * 4 + r;
        float av[8], bv[8], cv[8];
#pragma unroll
        for (int jj = 0; jj < 8; jj++) {
            cv[jj] = acc[2][r][jj];
            av[jj] = acc[0][r][jj] - cv[jj] + bias[c0 + jj];
            bv[jj] = acc[1][r][jj];
        }
        *(float4*)(outA + m * CO + c0)     = (float4){av[0], av[1], av[2], av[3]};
        *(float4*)(outA + m * CO + c0 + 4) = (float4){av[4], av[5], av[6], av[7]};
        float* bc = outBC + m * 2 * CO;
        *(float4*)(bc + c0)          = (float4){bv[0], bv[1], bv[2], bv[3]};
        *(float4*)(bc + c0 + 4)      = (float4){bv[4], bv[5], bv[6], bv[7]};
        *(float4*)(bc + CO + c0)     = (float4){cv[0], cv[1], cv[2], cv[3]};
        *(float4*)(bc + CO + c0 + 4) = (float4){cv[4], cv[5], cv[6], cv[7]};
    }
}

// ---------------- W-commute small GEMM (CI=32, CO=16, layer 3) ----------------
__global__ __launch_bounds__(256) void k_cheb_smallABC(const float* __restrict__ t0,
                                                       const float* __restrict__ W,
                                                       const float* __restrict__ bias,
                                                       float* __restrict__ outA,
                                                       float* __restrict__ outBC) {
    constexpr int CI = 32, CO = 16, MT = 256, AST = 33;
    __shared__ float At[MT * AST];      // 33.8 KB
    __shared__ float Ws[3 * CI * CO];   // 6 KB

    const int tid = threadIdx.x;
    const int cg = tid & 1;
    const int rg = tid >> 1;
    const int c0 = cg * 8;
    const int m_base = blockIdx.x * MT;

    for (int i = tid; i < 384; i += 256)
        ((float4*)Ws)[i] = ((const float4*)W)[i];

    // stage A tile: 256 rows x 32 k, coalesced
#pragma unroll
    for (int it = 0; it < 8; it++) {
        int idx = tid + it * 256;
        int row = idx >> 3, k4 = (idx & 7) * 4;
        float4 a = *(const float4*)(t0 + (size_t)(m_base + row) * CI + k4);
        float* dst = At + row * AST + k4;
        dst[0] = a.x; dst[1] = a.y; dst[2] = a.z; dst[3] = a.w;
    }
    __syncthreads();

    float acc[3][2][8] = {};
#pragma unroll 4
    for (int k = 0; k < CI; k++) {
        float a0 = At[rg * AST + k];
        float a1 = At[(rg + 128) * AST + k];
#pragma unroll
        for (int t = 0; t < 3; t++) {
            float4 w0 = *(const float4*)(Ws + t * CI * CO + k * CO + c0);
            float4 w1 = *(const float4*)(Ws + t * CI * CO + k * CO + c0 + 4);
            float wv[8] = {w0.x, w0.y, w0.z, w0.w, w1.x, w1.y, w1.z, w1.w};
#pragma unroll
            for (int jj = 0; jj < 8; jj++) {
                acc[t][0][jj] = fmaf(a0, wv[jj], acc[t][0][jj]);
                acc[t][1][jj] = fmaf(a1, wv[jj], acc[t][1][jj]);
            }
        }
    }

#pragma unroll
    for (int r = 0; r < 2; r++) {
        size_t m = m_base + rg + r * 128;
        float av[8], bv[8], cv[8];
#pragma unroll
        for (int jj = 0; jj < 8; jj++) {
            cv[jj] = acc[2][r][jj];
            av[jj] = acc[0][r][jj] - cv[jj] + bias[c0 + jj];
            bv[jj] = acc[1][r][jj];
        }
        *(float4*)(outA + m * CO + c0)     = (float4){av[0], av[1], av[2], av[3]};
        *(float4*)(outA + m * CO + c0 + 4) = (float4){av[4], av[5], av[6], av[7]};
        float* bc = outBC + m * 2 * CO;
        *(float4*)(bc + c0)          = (float4){bv[0], bv[1], bv[2], bv[3]};
        *(float4*)(bc + c0 + 4)      = (float4){bv[4], bv[5], bv[6], bv[7]};
        *(float4*)(bc + CO + c0)     = (float4){cv[0], cv[1], cv[2], cv[3]};
        *(float4*)(bc + CO + c0 + 4) = (float4){cv[4], cv[5], cv[6], cv[7]};
    }
}

// ---------------- prop+combine: out = lrelu(A + PB + 2*P(PC)), optional repeat ---------
// pbc holds [PB | PC] interleaved per node ([m][2CO]); gathers PC slice only.
template <int CO, bool REPEAT>
__global__ __launch_bounds__(256) void k_prop_comb(const float* __restrict__ pbc,
                                                   const float* __restrict__ a,
                                                   const int* __restrict__ row_ptr,
                                                   const int* __restrict__ col,
                                                   const float* __restrict__ val,
                                                   float* __restrict__ out, int n) {
    constexpr int C4 = CO / 4;
    constexpr int BY = 256 / C4;
    int c4 = threadIdx.x;
    int d = blockIdx.x;
    int b = blockIdx.y * BY + threadIdx.y;
    int p0 = row_ptr[d], p1 = row_ptr[d + 1];
    float4 acc = {0.f, 0.f, 0.f, 0.f};
    const float4* pb4 = (const float4*)pbc + (size_t)b * n * (2 * C4);
    for (int p = p0; p < p1; p++) {
        float vp = val[p];
        float4 hv = pb4[(size_t)col[p] * (2 * C4) + C4 + c4];   // PC slice
        acc.x = fmaf(vp, hv.x, acc.x);
        acc.y = fmaf(vp, hv.y, acc.y);
        acc.z = fmaf(vp, hv.z, acc.z);
        acc.w = fmaf(vp, hv.w, acc.w);
    }
    size_t node = (size_t)b * n + d;
    float4 av = ((const float4*)a)[node * C4 + c4];
    float4 pbv = pb4[(size_t)d * (2 * C4) + c4];                // PB at this node
    float4 f;
    f.x = av.x + pbv.x + 2.f * acc.x;
    f.y = av.y + pbv.y + 2.f * acc.y;
    f.z = av.z + pbv.z + 2.f * acc.z;
    f.w = av.w + pbv.w + 2.f * acc.w;
    f.x = f.x >= 0.f ? f.x : 0.2f * f.x;
    f.y = f.y >= 0.f ? f.y : 0.2f * f.y;
    f.z = f.z >= 0.f ? f.z : 0.2f * f.z;
    f.w = f.w >= 0.f ? f.w : 0.2f * f.w;
    if (REPEAT) {
        size_t o = ((size_t)b * 2 * n + 2 * d) * C4 + c4;
        ((float4*)out)[o] = f;
        ((float4*)out)[o + C4] = f;
    } else {
        ((float4*)out)[node * C4 + c4] = f;
    }
}

// ---------------- final conv: ci=16, co=3 ----------------
__global__ __launch_bounds__(256) void k_final_conv(const float* __restrict__ t0,
                                                    const float* __restrict__ t1,
                                                    const float* __restrict__ t2,
                                                    const float* __restrict__ W,
                                                    const float* __restrict__ bias,
                                                    float* __restrict__ out, int M) {
    int m = blockIdx.x * 256 + threadIdx.x;
    if (m >= M) return;
    float a0 = bias[0], a1 = bias[1], a2 = bias[2];
    const float* hs[3] = {t0, t1, t2};
#pragma unroll
    for (int t = 0; t < 3; t++) {
        const float4* h4 = (const float4*)(hs[t] + (size_t)m * 16);
        const float* Wt = W + t * 48;
#pragma unroll
        for (int q = 0; q < 4; q++) {
            float4 hv = h4[q];
            const float* Wq = Wt + q * 12;
            a0 = fmaf(hv.x, Wq[0], a0); a1 = fmaf(hv.x, Wq[1], a1); a2 = fmaf(hv.x, Wq[2], a2);
            a0 = fmaf(hv.y, Wq[3], a0); a1 = fmaf(hv.y, Wq[4], a1); a2 = fmaf(hv.y, Wq[5], a2);
            a0 = fmaf(hv.z, Wq[6], a0); a1 = fmaf(hv.z, Wq[7], a1); a2 = fmaf(hv.z, Wq[8], a2);
            a0 = fmaf(hv.w, Wq[9], a0); a1 = fmaf(hv.w, Wq[10], a1); a2 = fmaf(hv.w, Wq[11], a2);
        }
    }
    out[(size_t)m * 3 + 0] = a0;
    out[(size_t)m * 3 + 1] = a1;
    out[(size_t)m * 3 + 2] = a2;
}

// ---------------- permute + slice (f32 output) ----------------
__global__ __launch_bounds__(256) void k_permute(const float* __restrict__ h,
                                                 const int* __restrict__ perm,
                                                 float* __restrict__ out) {
    const int V = 6890, N = 6912;
    int idx = blockIdx.x * 256 + threadIdx.x;
    if (idx >= 128 * V * 3) return;
    int c = idx % 3;
    int t = idx / 3;
    int v = t % V;
    int b = t / V;
    int p = perm[v];
    out[idx] = h[((size_t)b * N + p) * 3 + c];
}

extern "C" void kernel_launch(void* const* d_in, const int* in_sizes, int n_in,
                              void* d_out, int out_size, void* d_ws, size_t ws_size,
                              hipStream_t stream) {
    float* out = (float*)d_out;

    static const int SIZES[20] = {
        16384, 65536, 512, 56623104, 110592,
        49152, 128, 24576, 64, 6144, 32, 1536, 16, 144, 3,
        10368, 20736, 41472, 82944, 6912
    };
    const void* in[20];
    bool map_ok = (n_in == 20);
    if (map_ok) {
        for (int s = 0; s < 20; s++) {
            int found = -1;
            for (int i = 0; i < n_in; i++)
                if (in_sizes[i] == SIZES[s]) { found = i; break; }
            if (found < 0) { map_ok = false; break; }
            in[s] = d_in[found];
        }
    }
    if (!map_ok)
        for (int i = 0; i < 20 && i < n_in; i++) in[i] = d_in[i];

    const float* x     = (const float*)in[0];
    const float* fc_w1 = (const float*)in[1];
    const float* fc_b1 = (const float*)in[2];
    const float* fc_w2 = (const float*)in[3];
    const float* fc_b2 = (const float*)in[4];
    const float* W0 = (const float*)in[5];
    const float* b0 = (const float*)in[6];
    const float* W1 = (const float*)in[7];
    const float* b1 = (const float*)in[8];
    const float* W2 = (const float*)in[9];
    const float* b2 = (const float*)in[10];
    const float* W3 = (const float*)in[11];
    const float* b3 = (const float*)in[12];
    const float* W4 = (const float*)in[13];
    const float* b4 = (const float*)in[14];

    const size_t SZ = 28311552;  // 128*1728*128 max buffer elems
    float* ws = (float*)d_ws;
    float* buf0 = ws;
    float* buf1 = ws + SZ;
    float* buf2 = ws + 2 * SZ;
    float* buf3 = ws + 3 * SZ;
    float* h1   = ws + 4 * SZ;           // 65536 (row-major [128][512])
    float* dinv = h1 + 65536;            // 6912
    float* val  = dinv + 6912;           // 41472
    int* ideg = (int*)(val + 41472);     // 6912
    int* rowp = ideg + 6912;             // 6913
    int* cnt  = rowp + 6913;             // 6912
    int* col  = cnt + 6912;              // 41472
    int* e0 = col + 41472;               // 10368
    int* e1 = e0 + 10368;                // 20736
    int* e2 = e1 + 20736;                // 41472
    int* e3 = e2 + 41472;                // 82944
    int* pm = e3 + 82944;                // 6912
    int* flag = pm + 6912;               // 1
    size_t needed = (char*)(flag + 1) - (char*)d_ws;
    if (ws_size < needed) {
        k_signal<<<1, 64, 0, stream>>>(out, 1000.0f);
        return;
    }

    // --- normalize integer inputs ---
    k_detect64<<<1, 64, 0, stream>>>((const long long*)in[15], 64, flag);
    k_cvt_idx<<<(10368 + 255) / 256, 256, 0, stream>>>(in[15], 10368, flag, e0);
    k_cvt_idx<<<(20736 + 255) / 256, 256, 0, stream>>>(in[16], 20736, flag, e1);
    k_cvt_idx<<<(41472 + 255) / 256, 256, 0, stream>>>(in[17], 41472, flag, e2);
    k_cvt_idx<<<(82944 + 255) / 256, 256, 0, stream>>>(in[18], 82944, flag, e3);
    k_cvt_idx<<<(6912 + 255) / 256, 256, 0, stream>>>(in[19], 6912, flag, pm);

    // FC1 + FC2 (v3, proven)
    k_fc1<<<dim3(2, 128), 256, 0, stream>>>(x, fc_w1, fc_b1, h1);
    k_fc2_gemm3<<<1728, 256, 0, stream>>>(h1, fc_w2, fc_b2, buf0);

    auto build = [&](const int* edge, int e, int n) {
        int nb_n = (n + 255) / 256, nb_e = (e + 255) / 256;
        k_zero_int<<<nb_n, 256, 0, stream>>>(ideg, n);
        k_zero_int<<<nb_n, 256, 0, stream>>>(cnt, n);
        k_deg<<<nb_e, 256, 0, stream>>>(edge + e, e, ideg);
        k_dinv<<<nb_n, 256, 0, stream>>>(ideg, dinv, n);
        k_scan<<<1, 256, 0, stream>>>(ideg, rowp, n);
        k_fill<<<nb_e, 256, 0, stream>>>(edge, edge + e, e, rowp, cnt, dinv, col, val);
    };

    // Layer 0 (ci=co=128, no commute win): old structure. buf0 -> buf3 (1728x128)
    build(e0, 6 * 864, 864);
    k_prop2<128, 0><<<dim3(864, 16), dim3(32, 8), 0, stream>>>(buf0, buf0, rowp, col, val, buf1, 864);
    k_prop2<128, 1><<<dim3(864, 16), dim3(32, 8), 0, stream>>>(buf1, buf0, rowp, col, val, buf2, 864);
    k_cheb_gemm3<128, 128, true><<<1728, 256, 0, stream>>>(buf0, buf1, buf2, W0, b0, buf3, 864);

    // Layer 1 (n=1728, ci=128, co=64), W-commute: gemmABC -> prop(BC) -> comb+repeat
    build(e1, 6 * 1728, 1728);
    k_cheb_gemmABC<128, 64><<<1728, 256, 0, stream>>>(buf3, W1, b1, buf1, buf2);
    k_prop2<128, 0><<<dim3(1728, 16), dim3(32, 8), 0, stream>>>(buf2, buf2, rowp, col, val, buf0, 1728);
    k_prop_comb<64, true><<<dim3(1728, 8), dim3(16, 16), 0, stream>>>(buf0, buf1, rowp, col, val, buf3, 1728);

    // Layer 2 (n=3456, ci=64, co=32), W-commute
    build(e2, 6 * 3456, 3456);
    k_cheb_gemmABC<64, 32><<<1728, 256, 0, stream>>>(buf3, W2, b2, buf1, buf2);
    k_prop2<64, 0><<<dim3(3456, 8), dim3(16, 16), 0, stream>>>(buf2, buf2, rowp, col, val, buf0, 3456);
    k_prop_comb<32, true><<<dim3(3456, 4), dim3(8, 32), 0, stream>>>(buf0, buf1, rowp, col, val, buf3, 3456);

    // Layer 3 (n=6912, ci=32, co=16, no repeat), W-commute
    build(e3, 6 * 6912, 6912);
    k_cheb_smallABC<<<3456, 256, 0, stream>>>(buf3, W3, b3, buf1, buf2);
    k_prop2<32, 0><<<dim3(6912, 4), dim3(8, 32), 0, stream>>>(buf2, buf2, rowp, col, val, buf0, 6912);
    k_prop_comb<16, false><<<dim3(6912, 2), dim3(4, 64), 0, stream>>>(buf0, buf1, rowp, col, val, buf3, 6912);

    // Layer 4 (ci=16, co=3): old structure, h in buf3
    k_prop2<16, 0><<<dim3(6912, 2), dim3(4, 64), 0, stream>>>(buf3, buf3, rowp, col, val, buf1, 6912);
    k_prop2<16, 1><<<dim3(6912, 2), dim3(4, 64), 0, stream>>>(buf1, buf3, rowp, col, val, buf2, 6912);
    k_final_conv<<<(884736 + 255) / 256, 256, 0, stream>>>(buf3, buf1, buf2, W4, b4, buf0, 884736);

    // Permute + slice, f32 output
    int tot = 128 * 6890 * 3;
    k_permute<<<(tot + 255) / 256, 256, 0, stream>>>(buf0, pm, out);

    if (!map_ok) k_signal<<<1, 64, 0, stream>>>(out, 2000.0f);
}

// Round 8
// 1728.688 us; speedup vs baseline: 1.2589x; 1.1351x over previous
//
#include <hip/hip_runtime.h>
#include <hip/hip_bf16.h>

#define DEVFN __device__ __forceinline__

// ---------------- debug signal ----------------
__global__ void k_signal(float* out, float v) {
    if (threadIdx.x == 0 && blockIdx.x == 0) out[0] = v;
}

// ---------------- int-width detect + normalize ----------------
__global__ void k_detect64(const long long* __restrict__ p, int count, int* flag) {
    if (threadIdx.x == 0 && blockIdx.x == 0) {
        int ok = 1;
        for (int i = 0; i < count; i++) {
            long long v = p[i];
            if (v < 0 || v >= (1LL << 30)) { ok = 0; break; }
        }
        *flag = ok;
    }
}

__global__ __launch_bounds__(256) void k_cvt_idx(const void* __restrict__ p, int n,
                                                 const int* __restrict__ flag,
                                                 int* __restrict__ out) {
    int i = blockIdx.x * 256 + threadIdx.x;
    if (i >= n) return;
    if (*flag) out[i] = (int)((const long long*)p)[i];
    else       out[i] = ((const int*)p)[i];
}

// ---------------- FC1: h1 = relu(x @ w1 + b1), (128,128)@(128,512), row-major ----------
__global__ __launch_bounds__(256) void k_fc1(const float* __restrict__ x,
                                             const float* __restrict__ w,
                                             const float* __restrict__ b,
                                             float* __restrict__ out) {
    int j = blockIdx.x * 256 + threadIdx.x;   // 512
    int m = blockIdx.y;                       // 128
    float acc = b[j];
    const float* xr = x + m * 128;
    for (int k = 0; k < 128; k++)
        acc = fmaf(xr[k], w[k * 512 + j], acc);
    out[m * 512 + j] = fmaxf(acc, 0.f);
}

// ---------------- FC2 LDS-tiled GEMM v3 (proven 194us): C[128,110592] ----------------
__global__ __launch_bounds__(256) void k_fc2_gemm3(const float* __restrict__ h1,
                                                   const float* __restrict__ w,
                                                   const float* __restrict__ bias,
                                                   float* __restrict__ out) {
    const int N = 110592, K = 512;
    constexpr int KT = 32, MT = 128, NT = 64, AST = 37;
    __shared__ float At[MT * AST];
    __shared__ float Bt[KT * NT];

    const int tid = threadIdx.x;
    const int cg = tid & 7;
    const int rg = tid >> 3;
    const int nbase = blockIdx.x * NT;
    const int c0 = cg * 8;

    float acc[4][8];
#pragma unroll
    for (int jj = 0; jj < 8; jj++) {
        float bj = bias[nbase + c0 + jj];
#pragma unroll
        for (int r = 0; r < 4; r++) acc[r][jj] = bj;
    }

    for (int k0 = 0; k0 < K; k0 += KT) {
        __syncthreads();
#pragma unroll
        for (int it = 0; it < 4; it++) {
            int idx = tid + it * 256;
            int row = idx >> 3, k4 = (idx & 7) * 4;
            float4 a = *(const float4*)(h1 + row * K + k0 + k4);
            float* dst = At + row * AST + k4;
            dst[0] = a.x; dst[1] = a.y; dst[2] = a.z; dst[3] = a.w;
        }
#pragma unroll
        for (int it = 0; it < 2; it++) {
            int idx = tid + it * 256;
            int kk = idx >> 4, c4 = (idx & 15) * 4;
            *(float4*)(Bt + kk * NT + c4) =
                *(const float4*)(w + (size_t)(k0 + kk) * N + nbase + c4);
        }
        __syncthreads();
#pragma unroll 4
        for (int k = 0; k < KT; k++) {
            float a0 = At[(rg * 4 + 0) * AST + k];
            float a1 = At[(rg * 4 + 1) * AST + k];
            float a2 = At[(rg * 4 + 2) * AST + k];
            float a3 = At[(rg * 4 + 3) * AST + k];
            float4 w0 = *(const float4*)(Bt + k * NT + c0);
            float4 w1 = *(const float4*)(Bt + k * NT + c0 + 4);
            float wv[8] = {w0.x, w0.y, w0.z, w0.w, w1.x, w1.y, w1.z, w1.w};
#pragma unroll
            for (int jj = 0; jj < 8; jj++) {
                acc[0][jj] = fmaf(a0, wv[jj], acc[0][jj]);
                acc[1][jj] = fmaf(a1, wv[jj], acc[1][jj]);
                acc[2][jj] = fmaf(a2, wv[jj], acc[2][jj]);
                acc[3][jj] = fmaf(a3, wv[jj], acc[3][jj]);
            }
        }
    }
#pragma unroll
    for (int r = 0; r < 4; r++) {
        int m = rg * 4 + r;
        float4 o0 = {acc[r][0], acc[r][1], acc[r][2], acc[r][3]};
        float4 o1 = {acc[r][4], acc[r][5], acc[r][6], acc[r][7]};
        *(float4*)(out + (size_t)m * N + nbase + c0) = o0;
        *(float4*)(out + (size_t)m * N + nbase + c0 + 4) = o1;
    }
}

// ---------------- graph build ----------------
__global__ __launch_bounds__(256) void k_zero_int(int* p, int n) {
    int i = blockIdx.x * 256 + threadIdx.x;
    if (i < n) p[i] = 0;
}

__global__ __launch_bounds__(256) void k_deg(const int* __restrict__ dst, int e,
                                             int* __restrict__ deg) {
    int i = blockIdx.x * 256 + threadIdx.x;
    if (i < e) atomicAdd(&deg[dst[i]], 1);
}

__global__ __launch_bounds__(256) void k_dinv(const int* __restrict__ deg,
                                              float* __restrict__ dinv, int n) {
    int i = blockIdx.x * 256 + threadIdx.x;
    if (i < n) dinv[i] = deg[i] > 0 ? 1.0f / sqrtf((float)deg[i]) : 0.0f;
}

__global__ __launch_bounds__(256) void k_scan(const int* __restrict__ deg,
                                              int* __restrict__ row_ptr, int n) {
    __shared__ int part[256];
    int tid = threadIdx.x;
    int per = (n + 255) / 256;
    int start = tid * per;
    int end = min(start + per, n);
    int s = 0;
    for (int i = start; i < end; i++) s += deg[i];
    part[tid] = s;
    __syncthreads();
    for (int off = 1; off < 256; off <<= 1) {
        int t = (tid >= off) ? part[tid - off] : 0;
        __syncthreads();
        part[tid] += t;
        __syncthreads();
    }
    int base = (tid == 0) ? 0 : part[tid - 1];
    int run = base;
    for (int i = start; i < end; i++) { row_ptr[i] = run; run += deg[i]; }
    if (tid == 255) row_ptr[n] = part[255];
}

__global__ __launch_bounds__(256) void k_fill(const int* __restrict__ src,
                                              const int* __restrict__ dst, int e,
                                              const int* __restrict__ row_ptr,
                                              int* __restrict__ cnt,
                                              const float* __restrict__ dinv,
                                              int* __restrict__ col, float* __restrict__ val) {
    int i = blockIdx.x * 256 + threadIdx.x;
    if (i >= e) return;
    int d = dst[i], s = src[i];
    int slot = row_ptr[d] + atomicAdd(&cnt[d], 1);
    col[slot] = s;
    val[slot] = -dinv[s] * dinv[d];
}

// ---------------- prop v2 (float4 channels) — used by L0 and L4 ----------------
template <int CI, int MODE>
__global__ __launch_bounds__(256) void k_prop2(const float* __restrict__ h,
                                               const float* __restrict__ sub,
                                               const int* __restrict__ row_ptr,
                                               const int* __restrict__ col,
                                               const float* __restrict__ val,
                                               float* __restrict__ out, int n) {
    constexpr int C4 = CI / 4;
    constexpr int BY = 256 / C4;
    int c4 = threadIdx.x;
    int d = blockIdx.x;
    int b = blockIdx.y * BY + threadIdx.y;
    int p0 = row_ptr[d], p1 = row_ptr[d + 1];
    float4 acc = {0.f, 0.f, 0.f, 0.f};
    const float4* hb = (const float4*)h + (size_t)b * n * C4;
    for (int p = p0; p < p1; p++) {
        float vp = val[p];
        float4 hv = hb[(size_t)col[p] * C4 + c4];
        acc.x = fmaf(vp, hv.x, acc.x);
        acc.y = fmaf(vp, hv.y, acc.y);
        acc.z = fmaf(vp, hv.z, acc.z);
        acc.w = fmaf(vp, hv.w, acc.w);
    }
    size_t oi = ((size_t)b * n + d) * C4 + c4;
    if (MODE) {
        float4 s = ((const float4*)sub)[oi];
        acc.x = 2.f * acc.x - s.x;
        acc.y = 2.f * acc.y - s.y;
        acc.z = 2.f * acc.z - s.z;
        acc.w = 2.f * acc.w - s.w;
    }
    ((float4*)out)[oi] = acc;
}

// ---------------- prop from COMPACT source: out[d] = sum val * src[col>>1] -------------
// src has n/2 node-rows (pre-repeat compact); out has n rows. CI = staged channels.
template <int CI>
__global__ __launch_bounds__(256) void k_prop_bc(const float* __restrict__ src,
                                                 const int* __restrict__ row_ptr,
                                                 const int* __restrict__ col,
                                                 const float* __restrict__ val,
                                                 float* __restrict__ out, int n) {
    constexpr int C4 = CI / 4;
    constexpr int BY = 256 / C4;
    int c4 = threadIdx.x;
    int d = blockIdx.x;
    int b = blockIdx.y * BY + threadIdx.y;
    int p0 = row_ptr[d], p1 = row_ptr[d + 1];
    float4 acc = {0.f, 0.f, 0.f, 0.f};
    const float4* hb = (const float4*)src + (size_t)b * (n >> 1) * C4;
    for (int p = p0; p < p1; p++) {
        float vp = val[p];
        float4 hv = hb[(size_t)(col[p] >> 1) * C4 + c4];
        acc.x = fmaf(vp, hv.x, acc.x);
        acc.y = fmaf(vp, hv.y, acc.y);
        acc.z = fmaf(vp, hv.z, acc.z);
        acc.w = fmaf(vp, hv.w, acc.w);
    }
    ((float4*)out)[((size_t)b * n + d) * C4 + c4] = acc;
}

// ------ prop+combine v2: out[d] = lrelu(A[d>>1] + PB[d] + 2*sum val*PC[col]) -----------
// pbc [b][n][2CO] full-width (PB|PC); a [b][n/2][CO] compact. Output full n, NO repeat
// (output is the next layer's compact input).
template <int CO>
__global__ __launch_bounds__(256) void k_prop_comb2(const float* __restrict__ pbc,
                                                    const float* __restrict__ a,
                                                    const int* __restrict__ row_ptr,
                                                    const int* __restrict__ col,
                                                    const float* __restrict__ val,
                                                    float* __restrict__ out, int n) {
    constexpr int C4 = CO / 4;
    constexpr int BY = 256 / C4;
    int c4 = threadIdx.x;
    int d = blockIdx.x;
    int b = blockIdx.y * BY + threadIdx.y;
    int p0 = row_ptr[d], p1 = row_ptr[d + 1];
    float4 acc = {0.f, 0.f, 0.f, 0.f};
    const float4* pb4 = (const float4*)pbc + (size_t)b * n * (2 * C4);
    for (int p = p0; p < p1; p++) {
        float vp = val[p];
        float4 hv = pb4[(size_t)col[p] * (2 * C4) + C4 + c4];   // PC slice
        acc.x = fmaf(vp, hv.x, acc.x);
        acc.y = fmaf(vp, hv.y, acc.y);
        acc.z = fmaf(vp, hv.z, acc.z);
        acc.w = fmaf(vp, hv.w, acc.w);
    }
    float4 av = ((const float4*)a)[((size_t)b * (n >> 1) + (d >> 1)) * C4 + c4];
    float4 pbv = pb4[(size_t)d * (2 * C4) + c4];                // PB at this node
    float4 f;
    f.x = av.x + pbv.x + 2.f * acc.x;
    f.y = av.y + pbv.y + 2.f * acc.y;
    f.z = av.z + pbv.z + 2.f * acc.z;
    f.w = av.w + pbv.w + 2.f * acc.w;
    f.x = f.x >= 0.f ? f.x : 0.2f * f.x;
    f.y = f.y >= 0.f ? f.y : 0.2f * f.y;
    f.z = f.z >= 0.f ? f.z : 0.2f * f.z;
    f.w = f.w >= 0.f ? f.w : 0.2f * f.w;
    ((float4*)out)[((size_t)b * n + d) * C4 + c4] = f;
}

// ---------------- cheb einsum GEMM v3 (layer 0 only, now REPEAT=false) ----------------
template <int CI, int CO, bool REPEAT>
__global__ __launch_bounds__(256) void k_cheb_gemm3(const float* __restrict__ t0,
                                                    const float* __restrict__ t1,
                                                    const float* __restrict__ t2,
                                                    const float* __restrict__ W,
                                                    const float* __restrict__ bias,
                                                    float* __restrict__ out, int n) {
    constexpr int CGN = CO / 8;
    constexpr int MT = 1024 / CGN;
    constexpr int KT = 32, AST = 37;
    __shared__ float At[MT * AST];
    __shared__ float Wt_s[KT * CO];

    const int tid = threadIdx.x;
    const int cg = tid % CGN;
    const int rg = tid / CGN;
    const int m_base = blockIdx.x * MT;
    const int c0 = cg * 8;

    float acc[4][8];
#pragma unroll
    for (int jj = 0; jj < 8; jj++) {
        float bj = bias[c0 + jj];
#pragma unroll
        for (int r = 0; r < 4; r++) acc[r][jj] = bj;
    }

    const float* As[3] = {t0, t1, t2};
#pragma unroll 1
    for (int t = 0; t < 3; t++) {
        const float* A = As[t];
        const float* Wg = W + t * CI * CO;
#pragma unroll 1
        for (int k0 = 0; k0 < CI; k0 += KT) {
            __syncthreads();
#pragma unroll
            for (int it = 0; it < MT / 32; it++) {
                int idx = tid + it * 256;
                int row = idx >> 3, k4 = (idx & 7) * 4;
                float4 a = *(const float4*)(A + (size_t)(m_base + row) * CI + k0 + k4);
                float* dst = At + row * AST + k4;
                dst[0] = a.x; dst[1] = a.y; dst[2] = a.z; dst[3] = a.w;
            }
#pragma unroll
            for (int it = 0; it < (KT * CO) / 1024; it++) {
                int idx = tid + it * 256;
                int kk = idx / (CO / 4), c4 = (idx % (CO / 4)) * 4;
                *(float4*)(Wt_s + kk * CO + c4) =
                    *(const float4*)(Wg + (k0 + kk) * CO + c4);
            }
            __syncthreads();
#pragma unroll 4
            for (int k = 0; k < KT; k++) {
                float a0 = At[(rg * 4 + 0) * AST + k];
                float a1 = At[(rg * 4 + 1) * AST + k];
                float a2 = At[(rg * 4 + 2) * AST + k];
                float a3 = At[(rg * 4 + 3) * AST + k];
                float4 w0 = *(const float4*)(Wt_s + k * CO + c0);
                float4 w1 = *(const float4*)(Wt_s + k * CO + c0 + 4);
                float wv[8] = {w0.x, w0.y, w0.z, w0.w, w1.x, w1.y, w1.z, w1.w};
#pragma unroll
                for (int jj = 0; jj < 8; jj++) {
                    acc[0][jj] = fmaf(a0, wv[jj], acc[0][jj]);
                    acc[1][jj] = fmaf(a1, wv[jj], acc[1][jj]);
                    acc[2][jj] = fmaf(a2, wv[jj], acc[2][jj]);
                    acc[3][jj] = fmaf(a3, wv[jj], acc[3][jj]);
                }
            }
        }
    }

#pragma unroll
    for (int r = 0; r < 4; r++) {
        int m = m_base + rg * 4 + r;
#pragma unroll
        for (int jj = 0; jj < 8; jj++) {
            float v = acc[r][jj];
            acc[r][jj] = v >= 0.f ? v : 0.2f * v;   // lrelu
        }
        float4 o0 = {acc[r][0], acc[r][1], acc[r][2], acc[r][3]};
        float4 o1 = {acc[r][4], acc[r][5], acc[r][6], acc[r][7]};
        if (REPEAT) {
            int b = m / n, d = m - (m / n) * n;
            size_t ob = ((size_t)b * (2 * n) + 2 * d) * CO + c0;
            *(float4*)(out + ob) = o0;
            *(float4*)(out + ob + 4) = o1;
            *(float4*)(out + ob + CO) = o0;
            *(float4*)(out + ob + CO + 4) = o1;
        } else {
            *(float4*)(out + (size_t)m * CO + c0) = o0;
            *(float4*)(out + (size_t)m * CO + c0 + 4) = o1;
        }
    }
}

// ---------------- W-commute GEMM: A = T0(W0-W2)+b, B = T0 W1, C = T0 W2 ----------------
template <int CI, int CO>
__global__ __launch_bounds__(256) void k_cheb_gemmABC(const float* __restrict__ t0,
                                                      const float* __restrict__ W,
                                                      const float* __restrict__ bias,
                                                      float* __restrict__ outA,
                                                      float* __restrict__ outBC) {
    constexpr int CGN = CO / 8;
    constexpr int MT = 1024 / CGN;
    constexpr int KT = 32, AST = 37;
    __shared__ float At[MT * AST];
    __shared__ float Ws[3 * KT * CO];

    const int tid = threadIdx.x;
    const int cg = tid % CGN;
    const int rg = tid / CGN;
    const int m_base = blockIdx.x * MT;
    const int c0 = cg * 8;

    float acc[3][4][8] = {};

#pragma unroll 1
    for (int k0 = 0; k0 < CI; k0 += KT) {
        __syncthreads();
#pragma unroll
        for (int it = 0; it < MT / 32; it++) {
            int idx = tid + it * 256;
            int row = idx >> 3, k4 = (idx & 7) * 4;
            float4 a = *(const float4*)(t0 + (size_t)(m_base + row) * CI + k0 + k4);
            float* dst = At + row * AST + k4;
            dst[0] = a.x; dst[1] = a.y; dst[2] = a.z; dst[3] = a.w;
        }
#pragma unroll
        for (int t = 0; t < 3; t++)
#pragma unroll
            for (int it = 0; it < CO / 32; it++) {
                int idx = tid + it * 256;
                int kk = idx / (CO / 4), c4 = (idx % (CO / 4)) * 4;
                *(float4*)(Ws + t * KT * CO + kk * CO + c4) =
                    *(const float4*)(W + t * CI * CO + (size_t)(k0 + kk) * CO + c4);
            }
        __syncthreads();
#pragma unroll 2
        for (int k = 0; k < KT; k++) {
            float a0 = At[(rg * 4 + 0) * AST + k];
            float a1 = At[(rg * 4 + 1) * AST + k];
            float a2 = At[(rg * 4 + 2) * AST + k];
            float a3 = At[(rg * 4 + 3) * AST + k];
#pragma unroll
            for (int t = 0; t < 3; t++) {
                float4 w0 = *(const float4*)(Ws + t * KT * CO + k * CO + c0);
                float4 w1 = *(const float4*)(Ws + t * KT * CO + k * CO + c0 + 4);
                float wv[8] = {w0.x, w0.y, w0.z, w0.w, w1.x, w1.y, w1.z, w1.w};
#pragma unroll
                for (int jj = 0; jj < 8; jj++) {
                    acc[t][0][jj] = fmaf(a0, wv[jj], acc[t][0][jj]);
                    acc[t][1][jj] = fmaf(a1, wv[jj], acc[t][1][jj]);
                    acc[t][2][jj] = fmaf(a2, wv[jj], acc[t][2][jj]);
                    acc[t][3][jj] = fmaf(a3, wv[jj], acc[t][3][jj]);
                }
            }
        }
    }

#pragma unroll
    for (int r = 0; r < 4; r++) {
        size_t m = m_base + rg * 4 + r;
        float av[8], bv[8], cv[8];
#pragma unroll
        for (int jj = 0; jj < 8; jj++) {
            cv[jj] = acc[2][r][jj];
            av[jj] = acc[0][r][jj] - cv[jj] + bias[c0 + jj];
            bv[jj] = acc[1][r][jj];
        }
        *(float4*)(outA + m * CO + c0)     = (float4){av[0], av[1], av[2], av[3]};
        *(float4*)(outA + m * CO + c0 + 4) = (float4){av[4], av[5], av[6], av[7]};
        float* bc = outBC + m * 2 * CO;
        *(float4*)(bc + c0)          = (float4){bv[0], bv[1], bv[2], bv[3]};
        *(float4*)(bc + c0 + 4)      = (float4){bv[4], bv[5], bv[6], bv[7]};
        *(float4*)(bc + CO + c0)     = (float4){cv[0], cv[1], cv[2], cv[3]};
        *(float4*)(bc + CO + c0 + 4) = (float4){cv[4], cv[5], cv[6], cv[7]};
    }
}

// ---------------- W-commute small GEMM (CI=32, CO=16, layer 3) ----------------
__global__ __launch_bounds__(256) void k_cheb_smallABC(const float* __restrict__ t0,
                                                       const float* __restrict__ W,
                                                       const float* __restrict__ bias,
                                                       float* __restrict__ outA,
                                                       float* __restrict__ outBC) {
    constexpr int CI = 32, CO = 16, MT = 256, AST = 33;
    __shared__ float At[MT * AST];
    __shared__ float Ws[3 * CI * CO];

    const int tid = threadIdx.x;
    const int cg = tid & 1;
    const int rg = tid >> 1;
    const int c0 = cg * 8;
    const int m_base = blockIdx.x * MT;

    for (int i = tid; i < 384; i += 256)
        ((float4*)Ws)[i] = ((const float4*)W)[i];

#pragma unroll
    for (int it = 0; it < 8; it++) {
        int idx = tid + it * 256;
        int row = idx >> 3, k4 = (idx & 7) * 4;
        float4 a = *(const float4*)(t0 + (size_t)(m_base + row) * CI + k4);
        float* dst = At + row * AST + k4;
        dst[0] = a.x; dst[1] = a.y; dst[2] = a.z; dst[3] = a.w;
    }
    __syncthreads();

    float acc[3][2][8] = {};
#pragma unroll 4
    for (int k = 0; k < CI; k++) {
        float a0 = At[rg * AST + k];
        float a1 = At[(rg + 128) * AST + k];
#pragma unroll
        for (int t = 0; t < 3; t++) {
            float4 w0 = *(const float4*)(Ws + t * CI * CO + k * CO + c0);
            float4 w1 = *(const float4*)(Ws + t * CI * CO + k * CO + c0 + 4);
            float wv[8] = {w0.x, w0.y, w0.z, w0.w, w1.x, w1.y, w1.z, w1.w};
#pragma unroll
            for (int jj = 0; jj < 8; jj++) {
                acc[t][0][jj] = fmaf(a0, wv[jj], acc[t][0][jj]);
                acc[t][1][jj] = fmaf(a1, wv[jj], acc[t][1][jj]);
            }
        }
    }

#pragma unroll
    for (int r = 0; r < 2; r++) {
        size_t m = m_base + rg + r * 128;
        float av[8], bv[8], cv[8];
#pragma unroll
        for (int jj = 0; jj < 8; jj++) {
            cv[jj] = acc[2][r][jj];
            av[jj] = acc[0][r][jj] - cv[jj] + bias[c0 + jj];
            bv[jj] = acc[1][r][jj];
        }
        *(float4*)(outA + m * CO + c0)     = (float4){av[0], av[1], av[2], av[3]};
        *(float4*)(outA + m * CO + c0 + 4) = (float4){av[4], av[5], av[6], av[7]};
        float* bc = outBC + m * 2 * CO;
        *(float4*)(bc + c0)          = (float4){bv[0], bv[1], bv[2], bv[3]};
        *(float4*)(bc + c0 + 4)      = (float4){bv[4], bv[5], bv[6], bv[7]};
        *(float4*)(bc + CO + c0)     = (float4){cv[0], cv[1], cv[2], cv[3]};
        *(float4*)(bc + CO + c0 + 4) = (float4){cv[4], cv[5], cv[6], cv[7]};
    }
}

// ---------------- final conv: ci=16, co=3 ----------------
__global__ __launch_bounds__(256) void k_final_conv(const float* __restrict__ t0,
                                                    const float* __restrict__ t1,
                                                    const float* __restrict__ t2,
                                                    const float* __restrict__ W,
                                                    const float* __restrict__ bias,
                                                    float* __restrict__ out, int M) {
    int m = blockIdx.x * 256 + threadIdx.x;
    if (m >= M) return;
    float a0 = bias[0], a1 = bias[1], a2 = bias[2];
    const float* hs[3] = {t0, t1, t2};
#pragma unroll
    for (int t = 0; t < 3; t++) {
        const float4* h4 = (const float4*)(hs[t] + (size_t)m * 16);
        const float* Wt = W + t * 48;
#pragma unroll
        for (int q = 0; q < 4; q++) {
            float4 hv = h4[q];
            const float* Wq = Wt + q * 12;
            a0 = fmaf(hv.x, Wq[0], a0); a1 = fmaf(hv.x, Wq[1], a1); a2 = fmaf(hv.x, Wq[2], a2);
            a0 = fmaf(hv.y, Wq[3], a0); a1 = fmaf(hv.y, Wq[4], a1); a2 = fmaf(hv.y, Wq[5], a2);
            a0 = fmaf(hv.z, Wq[6], a0); a1 = fmaf(hv.z, Wq[7], a1); a2 = fmaf(hv.z, Wq[8], a2);
            a0 = fmaf(hv.w, Wq[9], a0); a1 = fmaf(hv.w, Wq[10], a1); a2 = fmaf(hv.w, Wq[11], a2);
        }
    }
    out[(size_t)m * 3 + 0] = a0;
    out[(size_t)m * 3 + 1] = a1;
    out[(size_t)m * 3 + 2] = a2;
}

// ---------------- permute + slice (f32 output) ----------------
__global__ __launch_bounds__(256) void k_permute(const float* __restrict__ h,
                                                 const int* __restrict__ perm,
                                                 float* __restrict__ out) {
    const int V = 6890, N = 6912;
    int idx = blockIdx.x * 256 + threadIdx.x;
    if (idx >= 128 * V * 3) return;
    int c = idx % 3;
    int t = idx / 3;
    int v = t % V;
    int b = t / V;
    int p = perm[v];
    out[idx] = h[((size_t)b * N + p) * 3 + c];
}

extern "C" void kernel_launch(void* const* d_in, const int* in_sizes, int n_in,
                              void* d_out, int out_size, void* d_ws, size_t ws_size,
                              hipStream_t stream) {
    float* out = (float*)d_out;

    static const int SIZES[20] = {
        16384, 65536, 512, 56623104, 110592,
        49152, 128, 24576, 64, 6144, 32, 1536, 16, 144, 3,
        10368, 20736, 41472, 82944, 6912
    };
    const void* in[20];
    bool map_ok = (n_in == 20);
    if (map_ok) {
        for (int s = 0; s < 20; s++) {
            int found = -1;
            for (int i = 0; i < n_in; i++)
                if (in_sizes[i] == SIZES[s]) { found = i; break; }
            if (found < 0) { map_ok = false; break; }
            in[s] = d_in[found];
        }
    }
    if (!map_ok)
        for (int i = 0; i < 20 && i < n_in; i++) in[i] = d_in[i];

    const float* x     = (const float*)in[0];
    const float* fc_w1 = (const float*)in[1];
    const float* fc_b1 = (const float*)in[2];
    const float* fc_w2 = (const float*)in[3];
    const float* fc_b2 = (const float*)in[4];
    const float* W0 = (const float*)in[5];
    const float* b0 = (const float*)in[6];
    const float* W1 = (const float*)in[7];
    const float* b1 = (const float*)in[8];
    const float* W2 = (const float*)in[9];
    const float* b2 = (const float*)in[10];
    const float* W3 = (const float*)in[11];
    const float* b3 = (const float*)in[12];
    const float* W4 = (const float*)in[13];
    const float* b4 = (const float*)in[14];

    const size_t SZ = 28311552;  // 128*1728*128 max buffer elems
    float* ws = (float*)d_ws;
    float* buf0 = ws;
    float* buf1 = ws + SZ;
    float* buf2 = ws + 2 * SZ;
    float* buf3 = ws + 3 * SZ;
    float* h1   = ws + 4 * SZ;           // 65536 (row-major [128][512])
    float* dinv = h1 + 65536;            // 6912
    float* val  = dinv + 6912;           // 41472
    int* ideg = (int*)(val + 41472);     // 6912
    int* rowp = ideg + 6912;             // 6913
    int* cnt  = rowp + 6913;             // 6912
    int* col  = cnt + 6912;              // 41472
    int* e0 = col + 41472;               // 10368
    int* e1 = e0 + 10368;                // 20736
    int* e2 = e1 + 20736;                // 41472
    int* e3 = e2 + 41472;                // 82944
    int* pm = e3 + 82944;                // 6912
    int* flag = pm + 6912;               // 1
    size_t needed = (char*)(flag + 1) - (char*)d_ws;
    if (ws_size < needed) {
        k_signal<<<1, 64, 0, stream>>>(out, 1000.0f);
        return;
    }

    // --- normalize integer inputs ---
    k_detect64<<<1, 64, 0, stream>>>((const long long*)in[15], 64, flag);
    k_cvt_idx<<<(10368 + 255) / 256, 256, 0, stream>>>(in[15], 10368, flag, e0);
    k_cvt_idx<<<(20736 + 255) / 256, 256, 0, stream>>>(in[16], 20736, flag, e1);
    k_cvt_idx<<<(41472 + 255) / 256, 256, 0, stream>>>(in[17], 41472, flag, e2);
    k_cvt_idx<<<(82944 + 255) / 256, 256, 0, stream>>>(in[18], 82944, flag, e3);
    k_cvt_idx<<<(6912 + 255) / 256, 256, 0, stream>>>(in[19], 6912, flag, pm);

    // FC1 + FC2 (v3, proven)
    k_fc1<<<dim3(2, 128), 256, 0, stream>>>(x, fc_w1, fc_b1, h1);
    k_fc2_gemm3<<<1728, 256, 0, stream>>>(h1, fc_w2, fc_b2, buf0);

    auto build = [&](const int* edge, int e, int n) {
        int nb_n = (n + 255) / 256, nb_e = (e + 255) / 256;
        k_zero_int<<<nb_n, 256, 0, stream>>>(ideg, n);
        k_zero_int<<<nb_n, 256, 0, stream>>>(cnt, n);
        k_deg<<<nb_e, 256, 0, stream>>>(edge + e, e, ideg);
        k_dinv<<<nb_n, 256, 0, stream>>>(ideg, dinv, n);
        k_scan<<<1, 256, 0, stream>>>(ideg, rowp, n);
        k_fill<<<nb_e, 256, 0, stream>>>(edge, edge + e, e, rowp, cnt, dinv, col, val);
    };

    // Layer 0 (n=864, ci=co=128): old 3-T structure, output COMPACT (no repeat).
    // buf0 (864x128) -> buf3 compact [128*864][128]
    build(e0, 6 * 864, 864);
    k_prop2<128, 0><<<dim3(864, 16), dim3(32, 8), 0, stream>>>(buf0, buf0, rowp, col, val, buf1, 864);
    k_prop2<128, 1><<<dim3(864, 16), dim3(32, 8), 0, stream>>>(buf1, buf0, rowp, col, val, buf2, 864);
    k_cheb_gemm3<128, 128, false><<<1728, 256, 0, stream>>>(buf0, buf1, buf2, W0, b0, buf3, 864);

    // Layer 1 (graph n=1728, compact input 864, ci=128, co=64):
    // gemmABC on compact (864 blocks) -> prop_bc (col>>1) -> comb2 (A[d>>1], no repeat)
    build(e1, 6 * 1728, 1728);
    k_cheb_gemmABC<128, 64><<<864, 256, 0, stream>>>(buf3, W1, b1, buf1, buf2);
    k_prop_bc<128><<<dim3(1728, 16), dim3(32, 8), 0, stream>>>(buf2, rowp, col, val, buf0, 1728);
    k_prop_comb2<64><<<dim3(1728, 8), dim3(16, 16), 0, stream>>>(buf0, buf1, rowp, col, val, buf3, 1728);

    // Layer 2 (graph n=3456, compact input 1728, ci=64, co=32)
    build(e2, 6 * 3456, 3456);
    k_cheb_gemmABC<64, 32><<<864, 256, 0, stream>>>(buf3, W2, b2, buf1, buf2);
    k_prop_bc<64><<<dim3(3456, 8), dim3(16, 16), 0, stream>>>(buf2, rowp, col, val, buf0, 3456);
    k_prop_comb2<32><<<dim3(3456, 4), dim3(8, 32), 0, stream>>>(buf0, buf1, rowp, col, val, buf3, 3456);

    // Layer 3 (graph n=6912, compact input 3456, ci=32, co=16)
    build(e3, 6 * 6912, 6912);
    k_cheb_smallABC<<<1728, 256, 0, stream>>>(buf3, W3, b3, buf1, buf2);
    k_prop_bc<32><<<dim3(6912, 4), dim3(8, 32), 0, stream>>>(buf2, rowp, col, val, buf0, 6912);
    k_prop_comb2<16><<<dim3(6912, 2), dim3(4, 64), 0, stream>>>(buf0, buf1, rowp, col, val, buf3, 6912);

    // Layer 4 (n=6912, ci=16, co=3): old structure, h in buf3 (full 6912, distinct)
    k_prop2<16, 0><<<dim3(6912, 2), dim3(4, 64), 0, stream>>>(buf3, buf3, rowp, col, val, buf1, 6912);
    k_prop2<16, 1><<<dim3(6912, 2), dim3(4, 64), 0, stream>>>(buf1, buf3, rowp, col, val, buf2, 6912);
    k_final_conv<<<(884736 + 255) / 256, 256, 0, stream>>>(buf3, buf1, buf2, W4, b4, buf0, 884736);

    // Permute + slice, f32 output
    int tot = 128 * 6890 * 3;
    k_permute<<<(tot + 255) / 256, 256, 0, stream>>>(buf0, pm, out);

    if (!map_ok) k_signal<<<1, 64, 0, stream>>>(out, 2000.0f);
}

// Round 10
// 1705.211 us; speedup vs baseline: 1.2762x; 1.0138x over previous
//
#include <hip/hip_runtime.h>
#include <hip/hip_bf16.h>

#define DEVFN __device__ __forceinline__

// ---------------- debug signal ----------------
__global__ void k_signal(float* out, float v) {
    if (threadIdx.x == 0 && blockIdx.x == 0) out[0] = v;
}

// ---------------- int-width detect + normalize ----------------
__global__ void k_detect64(const long long* __restrict__ p, int count, int* flag) {
    if (threadIdx.x == 0 && blockIdx.x == 0) {
        int ok = 1;
        for (int i = 0; i < count; i++) {
            long long v = p[i];
            if (v < 0 || v >= (1LL << 30)) { ok = 0; break; }
        }
        *flag = ok;
    }
}

__global__ __launch_bounds__(256) void k_cvt_idx(const void* __restrict__ p, int n,
                                                 const int* __restrict__ flag,
                                                 int* __restrict__ out) {
    int i = blockIdx.x * 256 + threadIdx.x;
    if (i >= n) return;
    if (*flag) out[i] = (int)((const long long*)p)[i];
    else       out[i] = ((const int*)p)[i];
}

// ---------------- FC1: h1 = relu(x @ w1 + b1), (128,128)@(128,512), row-major ----------
__global__ __launch_bounds__(256) void k_fc1(const float* __restrict__ x,
                                             const float* __restrict__ w,
                                             const float* __restrict__ b,
                                             float* __restrict__ out) {
    int j = blockIdx.x * 256 + threadIdx.x;   // 512
    int m = blockIdx.y;                       // 128
    float acc = b[j];
    const float* xr = x + m * 128;
    for (int k = 0; k < 128; k++)
        acc = fmaf(xr[k], w[k * 512 + j], acc);
    out[m * 512 + j] = fmaxf(acc, 0.f);
}

// ---------------- FC2 LDS-tiled GEMM v3 (proven 194us): C[128,110592] ----------------
__global__ __launch_bounds__(256) void k_fc2_gemm3(const float* __restrict__ h1,
                                                   const float* __restrict__ w,
                                                   const float* __restrict__ bias,
                                                   float* __restrict__ out) {
    const int N = 110592, K = 512;
    constexpr int KT = 32, MT = 128, NT = 64, AST = 37;
    __shared__ float At[MT * AST];
    __shared__ float Bt[KT * NT];

    const int tid = threadIdx.x;
    const int cg = tid & 7;
    const int rg = tid >> 3;
    const int nbase = blockIdx.x * NT;
    const int c0 = cg * 8;

    float acc[4][8];
#pragma unroll
    for (int jj = 0; jj < 8; jj++) {
        float bj = bias[nbase + c0 + jj];
#pragma unroll
        for (int r = 0; r < 4; r++) acc[r][jj] = bj;
    }

    for (int k0 = 0; k0 < K; k0 += KT) {
        __syncthreads();
#pragma unroll
        for (int it = 0; it < 4; it++) {
            int idx = tid + it * 256;
            int row = idx >> 3, k4 = (idx & 7) * 4;
            float4 a = *(const float4*)(h1 + row * K + k0 + k4);
            float* dst = At + row * AST + k4;
            dst[0] = a.x; dst[1] = a.y; dst[2] = a.z; dst[3] = a.w;
        }
#pragma unroll
        for (int it = 0; it < 2; it++) {
            int idx = tid + it * 256;
            int kk = idx >> 4, c4 = (idx & 15) * 4;
            *(float4*)(Bt + kk * NT + c4) =
                *(const float4*)(w + (size_t)(k0 + kk) * N + nbase + c4);
        }
        __syncthreads();
#pragma unroll 4
        for (int k = 0; k < KT; k++) {
            float a0 = At[(rg * 4 + 0) * AST + k];
            float a1 = At[(rg * 4 + 1) * AST + k];
            float a2 = At[(rg * 4 + 2) * AST + k];
            float a3 = At[(rg * 4 + 3) * AST + k];
            float4 w0 = *(const float4*)(Bt + k * NT + c0);
            float4 w1 = *(const float4*)(Bt + k * NT + c0 + 4);
            float wv[8] = {w0.x, w0.y, w0.z, w0.w, w1.x, w1.y, w1.z, w1.w};
#pragma unroll
            for (int jj = 0; jj < 8; jj++) {
                acc[0][jj] = fmaf(a0, wv[jj], acc[0][jj]);
                acc[1][jj] = fmaf(a1, wv[jj], acc[1][jj]);
                acc[2][jj] = fmaf(a2, wv[jj], acc[2][jj]);
                acc[3][jj] = fmaf(a3, wv[jj], acc[3][jj]);
            }
        }
    }
#pragma unroll
    for (int r = 0; r < 4; r++) {
        int m = rg * 4 + r;
        float4 o0 = {acc[r][0], acc[r][1], acc[r][2], acc[r][3]};
        float4 o1 = {acc[r][4], acc[r][5], acc[r][6], acc[r][7]};
        *(float4*)(out + (size_t)m * N + nbase + c0) = o0;
        *(float4*)(out + (size_t)m * N + nbase + c0 + 4) = o1;
    }
}

// ---------------- graph build ----------------
__global__ __launch_bounds__(256) void k_zero_int(int* p, int n) {
    int i = blockIdx.x * 256 + threadIdx.x;
    if (i < n) p[i] = 0;
}

__global__ __launch_bounds__(256) void k_deg(const int* __restrict__ dst, int e,
                                             int* __restrict__ deg) {
    int i = blockIdx.x * 256 + threadIdx.x;
    if (i < e) atomicAdd(&deg[dst[i]], 1);
}

__global__ __launch_bounds__(256) void k_dinv(const int* __restrict__ deg,
                                              float* __restrict__ dinv, int n) {
    int i = blockIdx.x * 256 + threadIdx.x;
    if (i < n) dinv[i] = deg[i] > 0 ? 1.0f / sqrtf((float)deg[i]) : 0.0f;
}

__global__ __launch_bounds__(256) void k_scan(const int* __restrict__ deg,
                                              int* __restrict__ row_ptr, int n) {
    __shared__ int part[256];
    int tid = threadIdx.x;
    int per = (n + 255) / 256;
    int start = tid * per;
    int end = min(start + per, n);
    int s = 0;
    for (int i = start; i < end; i++) s += deg[i];
    part[tid] = s;
    __syncthreads();
    for (int off = 1; off < 256; off <<= 1) {
        int t = (tid >= off) ? part[tid - off] : 0;
        __syncthreads();
        part[tid] += t;
        __syncthreads();
    }
    int base = (tid == 0) ? 0 : part[tid - 1];
    int run = base;
    for (int i = start; i < end; i++) { row_ptr[i] = run; run += deg[i]; }
    if (tid == 255) row_ptr[n] = part[255];
}

__global__ __launch_bounds__(256) void k_fill(const int* __restrict__ src,
                                              const int* __restrict__ dst, int e,
                                              const int* __restrict__ row_ptr,
                                              int* __restrict__ cnt,
                                              const float* __restrict__ dinv,
                                              int* __restrict__ col, float* __restrict__ val) {
    int i = blockIdx.x * 256 + threadIdx.x;
    if (i >= e) return;
    int d = dst[i], s = src[i];
    int slot = row_ptr[d] + atomicAdd(&cnt[d], 1);
    col[slot] = s;
    val[slot] = -dinv[s] * dinv[d];
}

// ---------------- prop v2 (float4 channels) — L0 and L4-PBC ----------------
template <int CI, int MODE>
__global__ __launch_bounds__(256) void k_prop2(const float* __restrict__ h,
                                               const float* __restrict__ sub,
                                               const int* __restrict__ row_ptr,
                                               const int* __restrict__ col,
                                               const float* __restrict__ val,
                                               float* __restrict__ out, int n) {
    constexpr int C4 = CI / 4;
    constexpr int BY = 256 / C4;
    int c4 = threadIdx.x;
    int d = blockIdx.x;
    int b = blockIdx.y * BY + threadIdx.y;
    int p0 = row_ptr[d], p1 = row_ptr[d + 1];
    float4 acc = {0.f, 0.f, 0.f, 0.f};
    const float4* hb = (const float4*)h + (size_t)b * n * C4;
    for (int p = p0; p < p1; p++) {
        float vp = val[p];
        float4 hv = hb[(size_t)col[p] * C4 + c4];
        acc.x = fmaf(vp, hv.x, acc.x);
        acc.y = fmaf(vp, hv.y, acc.y);
        acc.z = fmaf(vp, hv.z, acc.z);
        acc.w = fmaf(vp, hv.w, acc.w);
    }
    size_t oi = ((size_t)b * n + d) * C4 + c4;
    if (MODE) {
        float4 s = ((const float4*)sub)[oi];
        acc.x = 2.f * acc.x - s.x;
        acc.y = 2.f * acc.y - s.y;
        acc.z = 2.f * acc.z - s.z;
        acc.w = 2.f * acc.w - s.w;
    }
    ((float4*)out)[oi] = acc;
}

// ---------------- prop from COMPACT source: out[d] = sum val * src[col>>1] -------------
template <int CI>
__global__ __launch_bounds__(256) void k_prop_bc(const float* __restrict__ src,
                                                 const int* __restrict__ row_ptr,
                                                 const int* __restrict__ col,
                                                 const float* __restrict__ val,
                                                 float* __restrict__ out, int n) {
    constexpr int C4 = CI / 4;
    constexpr int BY = 256 / C4;
    int c4 = threadIdx.x;
    int d = blockIdx.x;
    int b = blockIdx.y * BY + threadIdx.y;
    int p0 = row_ptr[d], p1 = row_ptr[d + 1];
    float4 acc = {0.f, 0.f, 0.f, 0.f};
    const float4* hb = (const float4*)src + (size_t)b * (n >> 1) * C4;
    for (int p = p0; p < p1; p++) {
        float vp = val[p];
        float4 hv = hb[(size_t)(col[p] >> 1) * C4 + c4];
        acc.x = fmaf(vp, hv.x, acc.x);
        acc.y = fmaf(vp, hv.y, acc.y);
        acc.z = fmaf(vp, hv.z, acc.z);
        acc.w = fmaf(vp, hv.w, acc.w);
    }
    ((float4*)out)[((size_t)b * n + d) * C4 + c4] = acc;
}

// ------ prop+combine v2: out[d] = lrelu(A[d>>1] + PB[d] + 2*sum val*PC[col]) -----------
template <int CO>
__global__ __launch_bounds__(256) void k_prop_comb2(const float* __restrict__ pbc,
                                                    const float* __restrict__ a,
                                                    const int* __restrict__ row_ptr,
                                                    const int* __restrict__ col,
                                                    const float* __restrict__ val,
                                                    float* __restrict__ out, int n) {
    constexpr int C4 = CO / 4;
    constexpr int BY = 256 / C4;
    int c4 = threadIdx.x;
    int d = blockIdx.x;
    int b = blockIdx.y * BY + threadIdx.y;
    int p0 = row_ptr[d], p1 = row_ptr[d + 1];
    float4 acc = {0.f, 0.f, 0.f, 0.f};
    const float4* pb4 = (const float4*)pbc + (size_t)b * n * (2 * C4);
    for (int p = p0; p < p1; p++) {
        float vp = val[p];
        float4 hv = pb4[(size_t)col[p] * (2 * C4) + C4 + c4];   // PC slice
        acc.x = fmaf(vp, hv.x, acc.x);
        acc.y = fmaf(vp, hv.y, acc.y);
        acc.z = fmaf(vp, hv.z, acc.z);
        acc.w = fmaf(vp, hv.w, acc.w);
    }
    float4 av = ((const float4*)a)[((size_t)b * (n >> 1) + (d >> 1)) * C4 + c4];
    float4 pbv = pb4[(size_t)d * (2 * C4) + c4];                // PB at this node
    float4 f;
    f.x = av.x + pbv.x + 2.f * acc.x;
    f.y = av.y + pbv.y + 2.f * acc.y;
    f.z = av.z + pbv.z + 2.f * acc.z;
    f.w = av.w + pbv.w + 2.f * acc.w;
    f.x = f.x >= 0.f ? f.x : 0.2f * f.x;
    f.y = f.y >= 0.f ? f.y : 0.2f * f.y;
    f.z = f.z >= 0.f ? f.z : 0.2f * f.z;
    f.w = f.w >= 0.f ? f.w : 0.2f * f.w;
    ((float4*)out)[((size_t)b * n + d) * C4 + c4] = f;
}

// ---------------- cheb einsum GEMM v3 (layer 0 only, REPEAT=false) ----------------
template <int CI, int CO, bool REPEAT>
__global__ __launch_bounds__(256) void k_cheb_gemm3(const float* __restrict__ t0,
                                                    const float* __restrict__ t1,
                                                    const float* __restrict__ t2,
                                                    const float* __restrict__ W,
                                                    const float* __restrict__ bias,
                                                    float* __restrict__ out, int n) {
    constexpr int CGN = CO / 8;
    constexpr int MT = 1024 / CGN;
    constexpr int KT = 32, AST = 37;
    __shared__ float At[MT * AST];
    __shared__ float Wt_s[KT * CO];

    const int tid = threadIdx.x;
    const int cg = tid % CGN;
    const int rg = tid / CGN;
    const int m_base = blockIdx.x * MT;
    const int c0 = cg * 8;

    float acc[4][8];
#pragma unroll
    for (int jj = 0; jj < 8; jj++) {
        float bj = bias[c0 + jj];
#pragma unroll
        for (int r = 0; r < 4; r++) acc[r][jj] = bj;
    }

    const float* As[3] = {t0, t1, t2};
#pragma unroll 1
    for (int t = 0; t < 3; t++) {
        const float* A = As[t];
        const float* Wg = W + t * CI * CO;
#pragma unroll 1
        for (int k0 = 0; k0 < CI; k0 += KT) {
            __syncthreads();
#pragma unroll
            for (int it = 0; it < MT / 32; it++) {
                int idx = tid + it * 256;
                int row = idx >> 3, k4 = (idx & 7) * 4;
                float4 a = *(const float4*)(A + (size_t)(m_base + row) * CI + k0 + k4);
                float* dst = At + row * AST + k4;
                dst[0] = a.x; dst[1] = a.y; dst[2] = a.z; dst[3] = a.w;
            }
#pragma unroll
            for (int it = 0; it < (KT * CO) / 1024; it++) {
                int idx = tid + it * 256;
                int kk = idx / (CO / 4), c4 = (idx % (CO / 4)) * 4;
                *(float4*)(Wt_s + kk * CO + c4) =
                    *(const float4*)(Wg + (k0 + kk) * CO + c4);
            }
            __syncthreads();
#pragma unroll 4
            for (int k = 0; k < KT; k++) {
                float a0 = At[(rg * 4 + 0) * AST + k];
                float a1 = At[(rg * 4 + 1) * AST + k];
                float a2 = At[(rg * 4 + 2) * AST + k];
                float a3 = At[(rg * 4 + 3) * AST + k];
                float4 w0 = *(const float4*)(Wt_s + k * CO + c0);
                float4 w1 = *(const float4*)(Wt_s + k * CO + c0 + 4);
                float wv[8] = {w0.x, w0.y, w0.z, w0.w, w1.x, w1.y, w1.z, w1.w};
#pragma unroll
                for (int jj = 0; jj < 8; jj++) {
                    acc[0][jj] = fmaf(a0, wv[jj], acc[0][jj]);
                    acc[1][jj] = fmaf(a1, wv[jj], acc[1][jj]);
                    acc[2][jj] = fmaf(a2, wv[jj], acc[2][jj]);
                    acc[3][jj] = fmaf(a3, wv[jj], acc[3][jj]);
                }
            }
        }
    }

#pragma unroll
    for (int r = 0; r < 4; r++) {
        int m = m_base + rg * 4 + r;
#pragma unroll
        for (int jj = 0; jj < 8; jj++) {
            float v = acc[r][jj];
            acc[r][jj] = v >= 0.f ? v : 0.2f * v;   // lrelu
        }
        float4 o0 = {acc[r][0], acc[r][1], acc[r][2], acc[r][3]};
        float4 o1 = {acc[r][4], acc[r][5], acc[r][6], acc[r][7]};
        if (REPEAT) {
            int b = m / n, d = m - (m / n) * n;
            size_t ob = ((size_t)b * (2 * n) + 2 * d) * CO + c0;
            *(float4*)(out + ob) = o0;
            *(float4*)(out + ob + 4) = o1;
            *(float4*)(out + ob + CO) = o0;
            *(float4*)(out + ob + CO + 4) = o1;
        } else {
            *(float4*)(out + (size_t)m * CO + c0) = o0;
            *(float4*)(out + (size_t)m * CO + c0 + 4) = o1;
        }
    }
}

// ---------------- W-commute GEMM: A = T0(W0-W2)+b, B = T0 W1, C = T0 W2 ----------------
template <int CI, int CO>
__global__ __launch_bounds__(256) void k_cheb_gemmABC(const float* __restrict__ t0,
                                                      const float* __restrict__ W,
                                                      const float* __restrict__ bias,
                                                      float* __restrict__ outA,
                                                      float* __restrict__ outBC) {
    constexpr int CGN = CO / 8;
    constexpr int MT = 1024 / CGN;
    constexpr int KT = 32, AST = 37;
    __shared__ float At[MT * AST];
    __shared__ float Ws[3 * KT * CO];

    const int tid = threadIdx.x;
    const int cg = tid % CGN;
    const int rg = tid / CGN;
    const int m_base = blockIdx.x * MT;
    const int c0 = cg * 8;

    float acc[3][4][8] = {};

#pragma unroll 1
    for (int k0 = 0; k0 < CI; k0 += KT) {
        __syncthreads();
#pragma unroll
        for (int it = 0; it < MT / 32; it++) {
            int idx = tid + it * 256;
            int row = idx >> 3, k4 = (idx & 7) * 4;
            float4 a = *(const float4*)(t0 + (size_t)(m_base + row) * CI + k0 + k4);
            float* dst = At + row * AST + k4;
            dst[0] = a.x; dst[1] = a.y; dst[2] = a.z; dst[3] = a.w;
        }
#pragma unroll
        for (int t = 0; t < 3; t++)
#pragma unroll
            for (int it = 0; it < CO / 32; it++) {
                int idx = tid + it * 256;
                int kk = idx / (CO / 4), c4 = (idx % (CO / 4)) * 4;
                *(float4*)(Ws + t * KT * CO + kk * CO + c4) =
                    *(const float4*)(W + t * CI * CO + (size_t)(k0 + kk) * CO + c4);
            }
        __syncthreads();
#pragma unroll 2
        for (int k = 0; k < KT; k++) {
            float a0 = At[(rg * 4 + 0) * AST + k];
            float a1 = At[(rg * 4 + 1) * AST + k];
            float a2 = At[(rg * 4 + 2) * AST + k];
            float a3 = At[(rg * 4 + 3) * AST + k];
#pragma unroll
            for (int t = 0; t < 3; t++) {
                float4 w0 = *(const float4*)(Ws + t * KT * CO + k * CO + c0);
                float4 w1 = *(const float4*)(Ws + t * KT * CO + k * CO + c0 + 4);
                float wv[8] = {w0.x, w0.y, w0.z, w0.w, w1.x, w1.y, w1.z, w1.w};
#pragma unroll
                for (int jj = 0; jj < 8; jj++) {
                    acc[t][0][jj] = fmaf(a0, wv[jj], acc[t][0][jj]);
                    acc[t][1][jj] = fmaf(a1, wv[jj], acc[t][1][jj]);
                    acc[t][2][jj] = fmaf(a2, wv[jj], acc[t][2][jj]);
                    acc[t][3][jj] = fmaf(a3, wv[jj], acc[t][3][jj]);
                }
            }
        }
    }

#pragma unroll
    for (int r = 0; r < 4; r++) {
        size_t m = m_base + rg * 4 + r;
        float av[8], bv[8], cv[8];
#pragma unroll
        for (int jj = 0; jj < 8; jj++) {
            cv[jj] = acc[2][r][jj];
            av[jj] = acc[0][r][jj] - cv[jj] + bias[c0 + jj];
            bv[jj] = acc[1][r][jj];
        }
        *(float4*)(outA + m * CO + c0)     = (float4){av[0], av[1], av[2], av[3]};
        *(float4*)(outA + m * CO + c0 + 4) = (float4){av[4], av[5], av[6], av[7]};
        float* bc = outBC + m * 2 * CO;
        *(float4*)(bc + c0)          = (float4){bv[0], bv[1], bv[2], bv[3]};
        *(float4*)(bc + c0 + 4)      = (float4){bv[4], bv[5], bv[6], bv[7]};
        *(float4*)(bc + CO + c0)     = (float4){cv[0], cv[1], cv[2], cv[3]};
        *(float4*)(bc + CO + c0 + 4) = (float4){cv[4], cv[5], cv[6], cv[7]};
    }
}

// ---------------- W-commute small GEMM (CI=32, CO=16, layer 3) ----------------
__global__ __launch_bounds__(256) void k_cheb_smallABC(const float* __restrict__ t0,
                                                       const float* __restrict__ W,
                                                       const float* __restrict__ bias,
                                                       float* __restrict__ outA,
                                                       float* __restrict__ outBC) {
    constexpr int CI = 32, CO = 16, MT = 256, AST = 33;
    __shared__ float At[MT * AST];
    __shared__ float Ws[3 * CI * CO];

    const int tid = threadIdx.x;
    const int cg = tid & 1;
    const int rg = tid >> 1;
    const int c0 = cg * 8;
    const int m_base = blockIdx.x * MT;

    for (int i = tid; i < 384; i += 256)
        ((float4*)Ws)[i] = ((const float4*)W)[i];

#pragma unroll
    for (int it = 0; it < 8; it++) {
        int idx = tid + it * 256;
        int row = idx >> 3, k4 = (idx & 7) * 4;
        float4 a = *(const float4*)(t0 + (size_t)(m_base + row) * CI + k4);
        float* dst = At + row * AST + k4;
        dst[0] = a.x; dst[1] = a.y; dst[2] = a.z; dst[3] = a.w;
    }
    __syncthreads();

    float acc[3][2][8] = {};
#pragma unroll 4
    for (int k = 0; k < CI; k++) {
        float a0 = At[rg * AST + k];
        float a1 = At[(rg + 128) * AST + k];
#pragma unroll
        for (int t = 0; t < 3; t++) {
            float4 w0 = *(const float4*)(Ws + t * CI * CO + k * CO + c0);
            float4 w1 = *(const float4*)(Ws + t * CI * CO + k * CO + c0 + 4);
            float wv[8] = {w0.x, w0.y, w0.z, w0.w, w1.x, w1.y, w1.z, w1.w};
#pragma unroll
            for (int jj = 0; jj < 8; jj++) {
                acc[t][0][jj] = fmaf(a0, wv[jj], acc[t][0][jj]);
                acc[t][1][jj] = fmaf(a1, wv[jj], acc[t][1][jj]);
            }
        }
    }

#pragma unroll
    for (int r = 0; r < 2; r++) {
        size_t m = m_base + rg + r * 128;
        float av[8], bv[8], cv[8];
#pragma unroll
        for (int jj = 0; jj < 8; jj++) {
            cv[jj] = acc[2][r][jj];
            av[jj] = acc[0][r][jj] - cv[jj] + bias[c0 + jj];
            bv[jj] = acc[1][r][jj];
        }
        *(float4*)(outA + m * CO + c0)     = (float4){av[0], av[1], av[2], av[3]};
        *(float4*)(outA + m * CO + c0 + 4) = (float4){av[4], av[5], av[6], av[7]};
        float* bc = outBC + m * 2 * CO;
        *(float4*)(bc + c0)          = (float4){bv[0], bv[1], bv[2], bv[3]};
        *(float4*)(bc + c0 + 4)      = (float4){bv[4], bv[5], bv[6], bv[7]};
        *(float4*)(bc + CO + c0)     = (float4){cv[0], cv[1], cv[2], cv[3]};
        *(float4*)(bc + CO + c0 + 4) = (float4){cv[4], cv[5], cv[6], cv[7]};
    }
}

// ---------------- L4 W-commute: A = h(W0-W2)+b [m][4], BC = [hW1|hW2] [m][8] -----------
// W: (3,16,3) row-major W[t*48 + k*3 + c]; pad channel 3 with 0.
__global__ __launch_bounds__(256) void k_final_ABC(const float* __restrict__ h,
                                                   const float* __restrict__ W,
                                                   const float* __restrict__ bias,
                                                   float* __restrict__ outA,
                                                   float* __restrict__ outBC, int M) {
    __shared__ float Ws[144];
    int tid = threadIdx.x;
    if (tid < 144) Ws[tid] = W[tid];
    __syncthreads();
    int m = blockIdx.x * 256 + tid;
    if (m >= M) return;
    const float4* h4 = (const float4*)(h + (size_t)m * 16);
    float hv[16];
#pragma unroll
    for (int q = 0; q < 4; q++) {
        float4 v = h4[q];
        hv[q * 4 + 0] = v.x; hv[q * 4 + 1] = v.y; hv[q * 4 + 2] = v.z; hv[q * 4 + 3] = v.w;
    }
    float t0a[3] = {0.f, 0.f, 0.f}, bv[3] = {0.f, 0.f, 0.f}, cv[3] = {0.f, 0.f, 0.f};
#pragma unroll
    for (int k = 0; k < 16; k++) {
        float x = hv[k];
#pragma unroll
        for (int c = 0; c < 3; c++) {
            t0a[c] = fmaf(x, Ws[k * 3 + c], t0a[c]);
            bv[c]  = fmaf(x, Ws[48 + k * 3 + c], bv[c]);
            cv[c]  = fmaf(x, Ws[96 + k * 3 + c], cv[c]);
        }
    }
    float4 av = {t0a[0] - cv[0] + bias[0], t0a[1] - cv[1] + bias[1],
                 t0a[2] - cv[2] + bias[2], 0.f};
    ((float4*)outA)[m] = av;
    float4* bc = (float4*)(outBC + (size_t)m * 8);
    bc[0] = (float4){bv[0], bv[1], bv[2], 0.f};
    bc[1] = (float4){cv[0], cv[1], cv[2], 0.f};
}

// ------- L4 combine + permute fused: out[b][v] = A[d] + PB[d] + 2*sum val*PC[col], -----
// d = perm[v]. Writes final f32 output directly (slice to V=6890).
__global__ __launch_bounds__(256) void k_final_comb(const float* __restrict__ pbc,
                                                    const float* __restrict__ a,
                                                    const int* __restrict__ row_ptr,
                                                    const int* __restrict__ col,
                                                    const float* __restrict__ val,
                                                    const int* __restrict__ perm,
                                                    float* __restrict__ out) {
    const int V = 6890, N = 6912;
    int idx = blockIdx.x * 256 + threadIdx.x;   // over 128*V
    if (idx >= 128 * V) return;
    int v = idx % V;
    int b = idx / V;
    int d = perm[v];
    int p0 = row_ptr[d], p1 = row_ptr[d + 1];
    const float4* pb4 = (const float4*)pbc + (size_t)b * N * 2;
    float ax = 0.f, ay = 0.f, az = 0.f;
    for (int p = p0; p < p1; p++) {
        float vp = val[p];
        float4 pc = pb4[(size_t)col[p] * 2 + 1];
        ax = fmaf(vp, pc.x, ax);
        ay = fmaf(vp, pc.y, ay);
        az = fmaf(vp, pc.z, az);
    }
    float4 av = ((const float4*)a)[(size_t)b * N + d];
    float4 pbv = pb4[(size_t)d * 2];
    out[(size_t)idx * 3 + 0] = av.x + pbv.x + 2.f * ax;
    out[(size_t)idx * 3 + 1] = av.y + pbv.y + 2.f * ay;
    out[(size_t)idx * 3 + 2] = av.z + pbv.z + 2.f * az;
}

extern "C" void kernel_launch(void* const* d_in, const int* in_sizes, int n_in,
                              void* d_out, int out_size, void* d_ws, size_t ws_size,
                              hipStream_t stream) {
    float* out = (float*)d_out;

    static const int SIZES[20] = {
        16384, 65536, 512, 56623104, 110592,
        49152, 128, 24576, 64, 6144, 32, 1536, 16, 144, 3,
        10368, 20736, 41472, 82944, 6912
    };
    const void* in[20];
    bool map_ok = (n_in == 20);
    if (map_ok) {
        for (int s = 0; s < 20; s++) {
            int found = -1;
            for (int i = 0; i < n_in; i++)
                if (in_sizes[i] == SIZES[s]) { found = i; break; }
            if (found < 0) { map_ok = false; break; }
            in[s] = d_in[found];
        }
    }
    if (!map_ok)
        for (int i = 0; i < 20 && i < n_in; i++) in[i] = d_in[i];

    const float* x     = (const float*)in[0];
    const float* fc_w1 = (const float*)in[1];
    const float* fc_b1 = (const float*)in[2];
    const float* fc_w2 = (const float*)in[3];
    const float* fc_b2 = (const float*)in[4];
    const float* W0 = (const float*)in[5];
    const float* b0 = (const float*)in[6];
    const float* W1 = (const float*)in[7];
    const float* b1 = (const float*)in[8];
    const float* W2 = (const float*)in[9];
    const float* b2 = (const float*)in[10];
    const float* W3 = (const float*)in[11];
    const float* b3 = (const float*)in[12];
    const float* W4 = (const float*)in[13];
    const float* b4 = (const float*)in[14];

    const size_t SZ = 28311552;  // 128*1728*128 max buffer elems
    float* ws = (float*)d_ws;
    float* buf0 = ws;
    float* buf1 = ws + SZ;
    float* buf2 = ws + 2 * SZ;
    float* buf3 = ws + 3 * SZ;
    float* h1   = ws + 4 * SZ;           // 65536 (row-major [128][512])
    float* dinv = h1 + 65536;            // 6912
    float* val  = dinv + 6912;           // 41472
    int* ideg = (int*)(val + 41472);     // 6912
    int* rowp = ideg + 6912;             // 6913
    int* cnt  = rowp + 6913;             // 6912
    int* col  = cnt + 6912;              // 41472
    int* e0 = col + 41472;               // 10368
    int* e1 = e0 + 10368;                // 20736
    int* e2 = e1 + 20736;                // 41472
    int* e3 = e2 + 41472;                // 82944
    int* pm = e3 + 82944;                // 6912
    int* flag = pm + 6912;               // 1
    size_t needed = (char*)(flag + 1) - (char*)d_ws;
    if (ws_size < needed) {
        k_signal<<<1, 64, 0, stream>>>(out, 1000.0f);
        return;
    }

    // --- normalize integer inputs ---
    k_detect64<<<1, 64, 0, stream>>>((const long long*)in[15], 64, flag);
    k_cvt_idx<<<(10368 + 255) / 256, 256, 0, stream>>>(in[15], 10368, flag, e0);
    k_cvt_idx<<<(20736 + 255) / 256, 256, 0, stream>>>(in[16], 20736, flag, e1);
    k_cvt_idx<<<(41472 + 255) / 256, 256, 0, stream>>>(in[17], 41472, flag, e2);
    k_cvt_idx<<<(82944 + 255) / 256, 256, 0, stream>>>(in[18], 82944, flag, e3);
    k_cvt_idx<<<(6912 + 255) / 256, 256, 0, stream>>>(in[19], 6912, flag, pm);

    // FC1 + FC2 (v3, proven)
    k_fc1<<<dim3(2, 128), 256, 0, stream>>>(x, fc_w1, fc_b1, h1);
    k_fc2_gemm3<<<1728, 256, 0, stream>>>(h1, fc_w2, fc_b2, buf0);

    auto build = [&](const int* edge, int e, int n) {
        int nb_n = (n + 255) / 256, nb_e = (e + 255) / 256;
        k_zero_int<<<nb_n, 256, 0, stream>>>(ideg, n);
        k_zero_int<<<nb_n, 256, 0, stream>>>(cnt, n);
        k_deg<<<nb_e, 256, 0, stream>>>(edge + e, e, ideg);
        k_dinv<<<nb_n, 256, 0, stream>>>(ideg, dinv, n);
        k_scan<<<1, 256, 0, stream>>>(ideg, rowp, n);
        k_fill<<<nb_e, 256, 0, stream>>>(edge, edge + e, e, rowp, cnt, dinv, col, val);
    };

    // Layer 0 (n=864, ci=co=128): old 3-T structure, output COMPACT (no repeat).
    build(e0, 6 * 864, 864);
    k_prop2<128, 0><<<dim3(864, 16), dim3(32, 8), 0, stream>>>(buf0, buf0, rowp, col, val, buf1, 864);
    k_prop2<128, 1><<<dim3(864, 16), dim3(32, 8), 0, stream>>>(buf1, buf0, rowp, col, val, buf2, 864);
    k_cheb_gemm3<128, 128, false><<<1728, 256, 0, stream>>>(buf0, buf1, buf2, W0, b0, buf3, 864);

    // Layer 1 (graph n=1728, compact input 864, ci=128, co=64)
    build(e1, 6 * 1728, 1728);
    k_cheb_gemmABC<128, 64><<<864, 256, 0, stream>>>(buf3, W1, b1, buf1, buf2);
    k_prop_bc<128><<<dim3(1728, 16), dim3(32, 8), 0, stream>>>(buf2, rowp, col, val, buf0, 1728);
    k_prop_comb2<64><<<dim3(1728, 8), dim3(16, 16), 0, stream>>>(buf0, buf1, rowp, col, val, buf3, 1728);

    // Layer 2 (graph n=3456, compact input 1728, ci=64, co=32)
    build(e2, 6 * 3456, 3456);
    k_cheb_gemmABC<64, 32><<<864, 256, 0, stream>>>(buf3, W2, b2, buf1, buf2);
    k_prop_bc<64><<<dim3(3456, 8), dim3(16, 16), 0, stream>>>(buf2, rowp, col, val, buf0, 3456);
    k_prop_comb2<32><<<dim3(3456, 4), dim3(8, 32), 0, stream>>>(buf0, buf1, rowp, col, val, buf3, 3456);

    // Layer 3 (graph n=6912, compact input 3456, ci=32, co=16)
    build(e3, 6 * 6912, 6912);
    k_cheb_smallABC<<<1728, 256, 0, stream>>>(buf3, W3, b3, buf1, buf2);
    k_prop_bc<32><<<dim3(6912, 4), dim3(8, 32), 0, stream>>>(buf2, rowp, col, val, buf0, 6912);
    k_prop_comb2<16><<<dim3(6912, 2), dim3(4, 64), 0, stream>>>(buf0, buf1, rowp, col, val, buf3, 6912);

    // Layer 4 (n=6912, ci=16, co=3), W-commute + fused permute:
    // ABC: h(buf3) -> A(buf1 [m][4]), BC(buf2 [m][8]); PBC = P*BC (prop2<8>);
    // comb: out[b][v] = A[perm[v]] + PB[perm[v]] + 2*P(PC)[perm[v]] -> d_out
    k_final_ABC<<<(884736 + 255) / 256, 256, 0, stream>>>(buf3, W4, b4, buf1, buf2, 884736);
    k_prop2<8, 0><<<dim3(6912, 1), dim3(2, 128), 0, stream>>>(buf2, buf2, rowp, col, val, buf0, 6912);
    k_final_comb<<<(128 * 6890 + 255) / 256, 256, 0, stream>>>(buf0, buf1, rowp, col, val, pm, out);

    if (!map_ok) k_signal<<<1, 64, 0, stream>>>(out, 2000.0f);
}